// Round 9
// baseline (317.977 us; speedup 1.0000x reference)
//
#include <hip/hip_runtime.h>
#include <hip/hip_bf16.h>

#define NB 8
#define CC 128
#define HH 112
#define WW 112
#define HWS (HH*WW)            // 12544
#define PLANE (CC*HWS)         // 1605632
#define TOT (NB*PLANE)         // 12845056
#define XP 116                 // padded x-extent: x+2k, x in [0,112), k in {0,1,2}
#define LROW 130               // LDS row stride in ushorts (65 words == 1 mod 32 -> conflict-free)
#define PLANEP ((size_t)HH*XP*CC)   // per-batch ushorts in Bpad = 1663488

typedef __attribute__((ext_vector_type(8))) short short8v;
typedef __attribute__((ext_vector_type(4))) float float4v;

__device__ __forceinline__ float bflo(unsigned u){ return __uint_as_float(u<<16); }
__device__ __forceinline__ float bfhi(unsigned u){ return __uint_as_float(u & 0xffff0000u); }
__device__ __forceinline__ float ldv(const float* p, size_t i){ return p[i]; }
__device__ __forceinline__ float ldv(const ushort* p, size_t i){ return __uint_as_float(((unsigned)p[i])<<16); }
__device__ __forceinline__ void ld8(const ushort* p, float* v){
    uint4 u0 = *((const uint4*)p);
    v[0]=bflo(u0.x); v[1]=bfhi(u0.x); v[2]=bflo(u0.y); v[3]=bfhi(u0.y);
    v[4]=bflo(u0.z); v[5]=bfhi(u0.z); v[6]=bflo(u0.w); v[7]=bfhi(u0.w);
}
__device__ __forceinline__ void ld8(const float* p, float* v){
    float4 a = *((const float4*)p); float4 b = *((const float4*)(p+4));
    v[0]=a.x; v[1]=a.y; v[2]=a.z; v[3]=a.w; v[4]=b.x; v[5]=b.y; v[6]=b.z; v[7]=b.w;
}
__device__ __forceinline__ void ld4(const float* p, float* v){
    float4 a = *((const float4*)p);
    v[0]=a.x; v[1]=a.y; v[2]=a.z; v[3]=a.w;
}
__device__ __forceinline__ void ld4(const ushort* p, float* v){
    uint2 u = *((const uint2*)p);
    v[0]=bflo(u.x); v[1]=bfhi(u.x); v[2]=bflo(u.y); v[3]=bfhi(u.y);
}
__device__ __forceinline__ ushort f2bf(float f){
    unsigned u = __float_as_uint(f);
    return (ushort)((u + 0x7fffu + ((u>>16)&1u)) >> 16);
}
__device__ __forceinline__ void stv(float* o, size_t i, float v){ o[i]=v; }
__device__ __forceinline__ void stv(ushort* o, size_t i, float v){ o[i]=f2bf(v); }
// fast sigmoid: 1/(1+e^-v) = rcp(1 + 2^(-v*log2e)); ~1ulp fp32 — invisible at bf16 output
__device__ __forceinline__ float fsigmoid(float v){
    float e = __builtin_amdgcn_exp2f(v * -1.44269504f);
    return __builtin_amdgcn_rcpf(1.f + e);
}
// raw bf16 fragment load (no convert round-trip) vs fp32 convert path
__device__ __forceinline__ short8v ldbf(const ushort* p){ return *((const short8v*)p); }
__device__ __forceinline__ short8v ldbf(const float* p){
    float v[8]; ld8(p, v);
    ushort tmp[8];
    #pragma unroll
    for (int j=0;j<8;j++) tmp[j]=f2bf(v[j]);
    return *((const short8v*)tmp);
}

// ---------------- K0: dtype probe. flag=1 -> inputs are fp32 ----------------
__global__ __launch_bounds__(256) void detect_k(const ushort* __restrict__ x, int* __restrict__ flag){
    __shared__ int cnt;
    if (threadIdx.x==0) cnt = 0;
    __syncthreads();
    int bad = 0;
    for (int i = threadIdx.x; i < 2048; i += 256){
        float v = ldv(x, i);
        if (!(v > -1e4f && v < 1e4f)) bad++;
    }
    atomicAdd(&cnt, bad);
    __syncthreads();
    if (threadIdx.x==0) *flag = (cnt > 64) ? 1 : 0;
}

// ---------------- KW1: Wpk[o][kappa=k*128+i] = bf16(w3[o,i,0,k]) ----------------
template<typename ET>
__device__ __forceinline__ void wpack_body(const ET* __restrict__ w3, ushort* __restrict__ Wpk){
    int idx = blockIdx.x*256 + threadIdx.x;
    if (idx < CC*384){
        int o = idx/384, kap = idx - o*384;
        int k = kap>>7, i = kap&127;
        Wpk[idx] = f2bf(ldv(w3, (o*128+i)*3 + k));
    }
}
__global__ __launch_bounds__(256) void wpack_k(const void* w3, ushort* Wpk, const int* fl){
    if (*fl) wpack_body((const float*)w3, Wpk); else wpack_body((const ushort*)w3, Wpk);
}

// ---------------- KB: Bpad[n][y][xp][i] = bf16(silu(x)[i, y, xp-2]), zeros at xp in {0,1,114,115} ----------
template<typename ET>
__device__ __forceinline__ void bpad_body(const ET* __restrict__ x, ushort* __restrict__ Bpad){
    int y = blockIdx.x, n = blockIdx.y;
    __shared__ ushort px[XP*LROW];
    const ET* xb = x + (size_t)n*PLANE + y*WW;
    for (int idx=threadIdx.x; idx<CC*28; idx+=256){      // x4-vectorized global reads
        int i = idx/28, xq = (idx - i*28)*4;
        float v[4]; ld4(xb + (size_t)i*HWS + xq, v);
        #pragma unroll
        for (int d=0;d<4;d++){
            float vv = v[d];
            px[(xq+d+2)*LROW + i] = f2bf(vv * fsigmoid(vv));
        }
    }
    for (int idx=threadIdx.x; idx<4*CC; idx+=256){
        int j = idx >> 7, i = idx & 127;
        int xp = (j<2) ? j : j+112;               // 0,1,114,115
        px[xp*LROW + i] = 0;
    }
    __syncthreads();
    ushort* ob = Bpad + ((size_t)n*HH + y)*XP*CC;
    for (int idx=threadIdx.x; idx<XP*16; idx+=256){
        int xp = idx >> 4, c8 = idx & 15;
        const ushort* pr = px + xp*LROW + c8*8;   // even ushort index -> 4B aligned
        uint4 v;
        v.x = *((const uint*)(pr+0));
        v.y = *((const uint*)(pr+2));
        v.z = *((const uint*)(pr+4));
        v.w = *((const uint*)(pr+6));
        *((uint4*)(ob + (size_t)xp*CC + c8*8)) = v;   // fully coalesced 1KB/wave
    }
}
__global__ __launch_bounds__(256) void bpad_k(const void* x, ushort* Bpad, const int* fl){
    if (*fl) bpad_body((const float*)x, Bpad); else bpad_body((const ushort*)x, Bpad);
}

// ---------------- K2: t3T[n][s][o] = A(128x384) * B(384 x s) — A in LDS, deep B prefetch ----------------
__global__ __launch_bounds__(256) void conv3mm_k(const ushort* __restrict__ Bpad, const ushort* __restrict__ Wpk,
                                                 ushort* __restrict__ t3T){
    int bx = blockIdx.x;        // 0..195
    int n  = blockIdx.y;
    int sbi = bx >> 1, oh = bx & 1;
    int wid = threadIdx.x >> 6, lane = threadIdx.x & 63;
    int l15 = lane & 15, quad = lane >> 4;
    __shared__ ushort Alds[24576];           // 48KB
    {   // cooperative stage: granule g -> (kcmt, l15, quad); 12 x 16B per thread, all in flight
        const int tid = threadIdx.x;
        uint4 tmp[12];
        #pragma unroll
        for (int it=0; it<12; it++){
            int g = it*256 + tid;
            int kcmt = g >> 6, sl = (g>>2)&15, sq = g&3;
            int kc = kcmt >> 2, mt = kcmt & 3;
            tmp[it] = *((const uint4*)(Wpk + (size_t)(oh*64 + mt*16 + sl)*384 + kc*32 + sq*8));
        }
        #pragma unroll
        for (int it=0; it<12; it++){
            int g = it*256 + tid;
            *((uint4*)(Alds + g*8)) = tmp[it];
        }
    }
    __syncthreads();

    int s0 = sbi*128 + wid*32;
    int s1 = s0 + l15, s2 = s1 + 16;
    int y1 = s1/WW, x1 = s1 - y1*WW;
    int y2 = s2/WW, x2 = s2 - y2*WW;
    const ushort* bb = Bpad + (size_t)n*PLANEP;
    const ushort* b1p = bb + ((size_t)y1*XP + x1)*CC + quad*8;
    const ushort* b2p = bb + ((size_t)y2*XP + x2)*CC + quad*8;
    const ushort* al = Alds + l15*32 + quad*8;

    float4v acc[4][2] = {};
    short8v BA[2][4], BB[2][4], a0[4], a1[4];

    auto ldb = [&](int g, short8v (&B)[2][4]){
        #pragma unroll
        for (int m=0;m<4;m++){
            B[0][m] = *((const short8v*)(b1p + g*256 + m*32));
            B[1][m] = *((const short8v*)(b2p + g*256 + m*32));
        }
    };
    auto lda = [&](int kc, short8v (&dst)[4]){
        #pragma unroll
        for (int mt=0;mt<4;mt++) dst[mt] = *((const short8v*)(al + (kc*4+mt)*512));
    };
    auto step = [&](const short8v (&a)[4], const short8v (&B)[2][4], int m){
        #pragma unroll
        for (int mt=0;mt<4;mt++){
            acc[mt][0] = __builtin_amdgcn_mfma_f32_16x16x32_bf16(a[mt], B[0][m], acc[mt][0],0,0,0);
            acc[mt][1] = __builtin_amdgcn_mfma_f32_16x16x32_bf16(a[mt], B[1][m], acc[mt][1],0,0,0);
        }
    };

    ldb(0, BA); lda(0, a0);
    ldb(1, BB);
    lda(1, a1);  step(a0, BA, 0);   // kc0
    lda(2, a0);  step(a1, BA, 1);   // kc1
    lda(3, a1);  step(a0, BA, 2);   // kc2
    lda(4, a0);  step(a1, BA, 3);   // kc3
    ldb(2, BA);                     // region 2 (BA free)
    lda(5, a1);  step(a0, BB, 0);   // kc4
    lda(6, a0);  step(a1, BB, 1);   // kc5
    lda(7, a1);  step(a0, BB, 2);   // kc6
    lda(8, a0);  step(a1, BB, 3);   // kc7
    lda(9, a1);  step(a0, BA, 0);   // kc8
    lda(10, a0); step(a1, BA, 1);   // kc9
    lda(11, a1); step(a0, BA, 2);   // kc10
                 step(a1, BA, 3);   // kc11

    ushort* tb = t3T + (size_t)n*PLANE;
    #pragma unroll
    for (int nt=0; nt<2; nt++){
        int s = s0 + nt*16 + l15;
        ushort* rowp = tb + (size_t)s*128 + oh*64 + quad*4;
        #pragma unroll
        for (int mt=0; mt<4; mt++){
            ushort4 v;
            v.x = f2bf(acc[mt][nt][0]); v.y = f2bf(acc[mt][nt][1]);
            v.z = f2bf(acc[mt][nt][2]); v.w = f2bf(acc[mt][nt][3]);
            *((ushort4*)(rowp + mt*16)) = v;
        }
    }
}

// ---------------- KWD: wdp[k*128+c] = w4[c,k] (fp32) ----------------
template<typename ET>
__device__ __forceinline__ void wdpack_body(const ET* __restrict__ w4, float* __restrict__ wdp){
    int idx = blockIdx.x*256 + threadIdx.x;
    if (idx < 896){ int k = idx >> 7, c = idx & 127; wdp[idx] = ldv(w4, c*7 + k); }
}
__global__ __launch_bounds__(256) void wdpack_k(const void* w4, float* wdp, const int* fl){
    if (*fl) wdpack_body((const float*)w4, wdp); else wdpack_body((const ushort*)w4, wdp);
}

// ---------------- K3: depthwise conv(7,1) dil=(3,1) pad=(9,0) on transposed layout, LDS-free ----------------
__global__ __launch_bounds__(256) void dwconvT_k(const ushort* __restrict__ t3T, const float* __restrict__ wdp,
                                                 ushort* __restrict__ t4T){
    int by = blockIdx.x, n = blockIdx.y;
    int y = (by>>3) + (by&7)*14;   // XCD-contiguous y chunks
    const ushort* tb = t3T + (size_t)n*PLANE;
    ushort* ob = t4T + (size_t)n*PLANE + (size_t)y*WW*128;
    for (int it = threadIdx.x; it < WW*16; it += 256){
        int c8 = it & 15, x = it >> 4;
        int coff = c8*8;
        float acc8[8] = {0.f,0.f,0.f,0.f,0.f,0.f,0.f,0.f};
        #pragma unroll
        for (int k=0;k<7;k++){
            int row = y - 9 + 3*k;
            if (row < 0 || row >= HH) continue;
            float v[8]; ld8(tb + ((size_t)row*WW + x)*128 + coff, v);
            const float* wp = wdp + k*128 + coff;
            #pragma unroll
            for (int j=0;j<8;j++) acc8[j] = fmaf(wp[j], v[j], acc8[j]);
        }
        ushort tmp[8];
        #pragma unroll
        for (int j=0;j<8;j++) tmp[j] = f2bf(acc8[j]);
        *((short8v*)(ob + (size_t)x*128 + coff)) = *((const short8v*)tmp);
    }
}

// ---------------- KW2: Wfb[o][cl*7+k] = bf16(w15[o, cl*7+k] * w10[32g+cl, k]) ----------------
template<typename ET>
__device__ __forceinline__ void fusew_body(const ET* __restrict__ w10, const ET* __restrict__ w15,
                                           ushort* __restrict__ Wfb){
    int idx = blockIdx.x*256+threadIdx.x;
    if (idx < CC*224){
        int o = idx / 224, r = idx - o*224;
        int g = o >> 5;
        int cl = r/7, k = r - cl*7;
        int c = g*32 + cl;
        Wfb[idx] = f2bf(ldv(w15, o*224 + r) * ldv(w10, c*7+k));
    }
}
__global__ __launch_bounds__(256) void fusew_k(const void* w10, const void* w15, ushort* Wfb, const int* fl){
    if (*fl) fusew_body((const float*)w10, (const float*)w15, Wfb);
    else     fusew_body((const ushort*)w10, (const ushort*)w15, Wfb);
}

// ---------------- KWA: Wfa fragment pack. A[w][k][q][mt][l15][j] over c'-aligned 32-blocks ----------------
__global__ __launch_bounds__(256) void wfapack_k(const ushort* __restrict__ Wfb, ushort* __restrict__ Wfa){
    int idx = blockIdx.x*256 + threadIdx.x;   // 4*7*2*2*16*32 = 57344
    if (idx >= 57344) return;
    int j   = idx & 31;
    int l15 = (idx >> 5) & 15;
    int mt  = (idx >> 9) & 1;
    int q   = (idx >> 10) & 1;
    int k   = (idx >> 11) % 7;
    int w   = idx / 14336;
    int o = w*32 + mt*16 + l15;
    int cl = -1;
    if (q==1){ if (j < 30) cl = j + 2; }
    else     { if (j >= 30) cl = j - 30; }
    Wfa[idx] = (cl >= 0) ? Wfb[o*224 + cl*7 + k] : (ushort)0;
}

// ---------------- K6 v6: uT[n, y, x, o] = sum_k Wfa_k * t4T[n, y+2k-6, x, :] ----------------
// DMA pipeline: global_load_lds (16B) direct into 3 rotating LDS buffers, counted vmcnt.
template<int ST0, int NST>
__device__ __forceinline__ void t15_body_v6(const ushort* __restrict__ tbase, const ushort* __restrict__ Wfa,
                                            ushort* __restrict__ urow, int y, int w, int l15, int quad,
                                            ushort* lds){
    int qlo = (w+3)&3;
    int tid = threadIdx.x;
    float4v acc[NST][2] = {};
    int klo = (y >= 6) ? 0 : ((7 - y) >> 1);
    int khi = min(6, (117 - y) >> 1);
    int nk = khi - klo;              // >= 3 always

    const int swz = (tid>>4)&7;      // pi xor mask (depends only on tid bits 4..6)
    const int wbase = tid & ~63;     // wid*64: wave-uniform granule base within a j-chunk

    auto dma_row = [&](int k, int bufi){
        const ushort* rs = tbase + ((size_t)(y + 2*k - 6)*WW + ST0*16)*128;
        #pragma unroll
        for (int j=0;j<NST;j++){
            int g  = j*256 + tid;
            int gs = g ^ swz;                                  // pre-swizzled source granule
            const ushort* gp = rs + (size_t)gs*8;              // per-lane global addr
            ushort* lp = lds + (size_t)bufi*8192 + (size_t)(j*256 + wbase)*8;  // wave-uniform LDS base
            __builtin_amdgcn_global_load_lds((const __attribute__((address_space(1))) void*)gp,
                                             (__attribute__((address_space(3))) void*)lp, 16, 0, 0);
        }
    };
    auto issueA = [&](int k, short8v (&A)[4]){
        const ushort* af = Wfa + (w*7 + k)*2048 + l15*32 + quad*8;
        A[0] = *((const short8v*)(af));
        A[1] = *((const short8v*)(af + 512));
        A[2] = *((const short8v*)(af + 1024));
        A[3] = *((const short8v*)(af + 1536));
    };
    auto domm = [&](int bufi, const short8v (&A)[4]){
        const ushort* lb = lds + bufi*8192;
        #pragma unroll
        for (int st=0; st<NST; st++){
            int xl = st*16 + l15;
            int g0 = xl*16 + qlo*4 + quad;  g0 ^= (g0>>4)&7;
            int g1 = xl*16 + w*4   + quad;  g1 ^= (g1>>4)&7;
            short8v B0 = *((const short8v*)(lb + g0*8));
            short8v B1 = *((const short8v*)(lb + g1*8));
            acc[st][0] = __builtin_amdgcn_mfma_f32_16x16x32_bf16(A[0], B0, acc[st][0], 0,0,0);
            acc[st][1] = __builtin_amdgcn_mfma_f32_16x16x32_bf16(A[1], B0, acc[st][1], 0,0,0);
            acc[st][0] = __builtin_amdgcn_mfma_f32_16x16x32_bf16(A[2], B1, acc[st][0], 0,0,0);
            acc[st][1] = __builtin_amdgcn_mfma_f32_16x16x32_bf16(A[3], B1, acc[st][1], 0,0,0);
        }
    };
    auto iter = [&](int i, short8v (&Acur)[4], short8v (&Anx)[4]){
        // steady: rows i+1 (NST) + A (4) are the only ops newer than row i's DMA
        if (i+2 <= nk){
            if constexpr (NST==4) asm volatile("s_waitcnt vmcnt(8)" ::: "memory");
            else                  asm volatile("s_waitcnt vmcnt(7)" ::: "memory");
        } else {
            asm volatile("s_waitcnt vmcnt(0)" ::: "memory");
        }
        __builtin_amdgcn_s_barrier();
        __builtin_amdgcn_sched_barrier(0);
        if (i+1 <= nk) issueA(klo+i+1, Anx);
        if (i+2 <= nk) dma_row(klo+i+2, (i+2)%3);   // buffer last read at iter i-1; safe after this barrier
        domm(i%3, Acur);
    };

    short8v A0[4], A1[4];
    // prolog: rows klo, klo+1 in flight; A(klo) issued last
    dma_row(klo,   0);
    dma_row(klo+1, 1);
    issueA(klo, A0);

    for (int i=0; i<=nk; i+=2){
        iter(i, A0, A1);
        if (i+1 <= nk) iter(i+1, A1, A0);
    }

    // transposed store: uT[(y*WW + s)*128 + o] — wave w fills its 64B d-chunk of each 256B row
    #pragma unroll
    for (int st=0; st<NST; st++){
        int s = (ST0 + st)*16 + l15;
        ushort* p = urow + (size_t)s*128 + w*32 + quad*4;
        #pragma unroll
        for (int mt=0; mt<2; mt++){
            ushort4 v;
            v.x = f2bf(acc[st][mt][0]); v.y = f2bf(acc[st][mt][1]);
            v.z = f2bf(acc[st][mt][2]); v.w = f2bf(acc[st][mt][3]);
            *((ushort4*)(p + mt*16)) = v;
        }
    }
}
__global__ __launch_bounds__(256) void t15v6_k(const ushort* __restrict__ t4T, const ushort* __restrict__ Wfa,
                                               ushort* __restrict__ uT){
    __shared__ ushort lds[3*8192];     // 48KB: 3 x 16KB row-slice buffers
    int bx = blockIdx.x, n = blockIdx.y;   // bx in [0, 224)
    int xh = bx & 1, byi = bx >> 1;
    int y = (byi>>3) + (byi&7)*14;         // XCD-contiguous y chunks; x-halves paired
    int w = threadIdx.x >> 6, lane = threadIdx.x & 63;
    int l15 = lane & 15, quad = lane >> 4;
    const ushort* tbase = t4T + (size_t)n*PLANE;
    ushort* urow = uT + (size_t)n*PLANE + (size_t)y*WW*128;
    if (xh == 0) t15_body_v6<0,4>(tbase, Wfa, urow, y, w, l15, quad, lds);
    else         t15_body_v6<4,3>(tbase, Wfa, urow, y, w, l15, quad, lds);
}

// ---------------- K4 v3: t5[n,ci,cj] += sum_s sigmoid(x[ci,s]) * x[cj,s] ----------------
// s-split x98 (128 s per block; slices BOTH operands -> no duplicated work), raw bf16 B loads,
// fast sigmoid on A. Wave: 32 ci x 128 cj, acc[2][8]. Grid 98x8 = 784 blocks (~3/CU).
template<typename ET>
__device__ __forceinline__ void t5mm_body(const ET* __restrict__ x, float* __restrict__ t5){
    int ks = blockIdx.x, n = blockIdx.y;    // ks 0..97, 12544 = 98*128
    int wid = threadIdx.x>>6, lane = threadIdx.x&63;
    int l15 = lane&15, quad = lane>>4;
    const ET* xn = x + (size_t)n*PLANE;
    float4v acc[2][8] = {};
    for (int t=0; t<4; t++){
        int sb = ks*128 + t*32 + quad*8;
        short8v afr[2];
        #pragma unroll
        for (int mt=0; mt<2; mt++){
            int row = wid*32 + mt*16 + l15;
            float v[8]; ld8(xn + (size_t)row*HWS + sb, v);
            ushort tmp[8];
            #pragma unroll
            for (int j=0;j<8;j++) tmp[j] = f2bf(fsigmoid(v[j]));
            afr[mt] = *((const short8v*)tmp);
        }
        #pragma unroll
        for (int nt=0; nt<8; nt++){
            int row = nt*16 + l15;
            short8v bfr = ldbf(xn + (size_t)row*HWS + sb);
            acc[0][nt] = __builtin_amdgcn_mfma_f32_16x16x32_bf16(afr[0], bfr, acc[0][nt], 0,0,0);
            acc[1][nt] = __builtin_amdgcn_mfma_f32_16x16x32_bf16(afr[1], bfr, acc[1][nt], 0,0,0);
        }
    }
    float* t5n = t5 + n*16384;
    #pragma unroll
    for (int mt=0; mt<2; mt++){
        #pragma unroll
        for (int nt=0; nt<8; nt++){
            #pragma unroll
            for (int r=0; r<4; r++){
                int ci = wid*32 + mt*16 + quad*4 + r;
                int cj = nt*16 + l15;
                atomicAdd(&t5n[ci*128 + cj], acc[mt][nt][r]);
            }
        }
    }
}
__global__ __launch_bounds__(256) void t5mm_k(const void* x, float* t5, const int* fl){
    if (*fl) t5mm_body((const float*)x, t5); else t5mm_body((const ushort*)x, t5);
}

// ---------------- KC: coefb[n][d][c] = bf16(w9[c,d] * t5[n,c,d] * sc) ----------------
template<typename ET>
__device__ __forceinline__ void coefb_body(const ET* __restrict__ w9, const float* __restrict__ t5,
                                           ushort* __restrict__ coefb){
    const float sc = 7.89181775e-4f;   // 1/(sqrt(12544)*sqrt(128))
    int idx = blockIdx.x*256 + threadIdx.x;   // over 8*16384
    int n = idx >> 14, rem = idx & 16383;
    int d = rem >> 7, c = rem & 127;
    coefb[idx] = f2bf(ldv(w9, c*128 + d) * t5[n*16384 + c*128 + d] * sc);
}
__global__ __launch_bounds__(256) void coefb_k(const void* w9, const float* t5, ushort* coefb, const int* fl){
    if (*fl) coefb_body((const float*)w9, t5, coefb); else coefb_body((const ushort*)w9, t5, coefb);
}

// ---------------- K5 (MFMA): out = uT[shifted] + coefb(128d x 128c) * silu(x)(128c x s) ----------------
// uT is s-major/channel-contiguous: the shifted read is 8B contiguous per (mt,nt) per lane.
template<typename OT>
__device__ __forceinline__ void final2_body(const ushort* __restrict__ Bpad, const ushort* __restrict__ coefb,
                                            const ushort* __restrict__ uT, OT* __restrict__ out){
    int sb = blockIdx.x, n = blockIdx.y;
    int wid = threadIdx.x>>6, lane = threadIdx.x&63;
    int l15 = lane&15, quad = lane>>4;
    int shalf = wid >> 1, ohalf = wid & 1;
    int s0 = sb*64 + shalf*32;
    int s1 = s0 + l15, s2 = s1 + 16;
    int y1 = s1/WW, x1 = s1 - y1*WW;
    int y2 = s2/WW, x2 = s2 - y2*WW;
    const ushort* bb = Bpad + (size_t)n*PLANEP;
    const ushort* b1p = bb + ((size_t)y1*XP + x1 + 2)*CC + quad*8;
    const ushort* b2p = bb + ((size_t)y2*XP + x2 + 2)*CC + quad*8;
    const ushort* abase = coefb + (size_t)n*16384 + (size_t)(ohalf*64 + l15)*128 + quad*8;
    float4v acc[4][2] = {};
    short8v bv0[4], bv1[4], aP[4], aQ[4];
    #pragma unroll
    for (int kc=0;kc<4;kc++){
        bv0[kc] = *((const short8v*)(b1p + kc*32));
        bv1[kc] = *((const short8v*)(b2p + kc*32));
    }
    auto lda = [&](int kc, short8v (&dst)[4]){
        #pragma unroll
        for (int mt=0;mt<4;mt++) dst[mt] = *((const short8v*)(abase + mt*16*128 + kc*32));
    };
    auto step = [&](const short8v (&a)[4], int kc){
        #pragma unroll
        for (int mt=0;mt<4;mt++){
            acc[mt][0] = __builtin_amdgcn_mfma_f32_16x16x32_bf16(a[mt], bv0[kc], acc[mt][0],0,0,0);
            acc[mt][1] = __builtin_amdgcn_mfma_f32_16x16x32_bf16(a[mt], bv1[kc], acc[mt][1],0,0,0);
        }
    };
    lda(0, aP);
    lda(1, aQ); step(aP, 0);
    lda(2, aP); step(aQ, 1);
    lda(3, aQ); step(aP, 2);
                step(aQ, 3);
    const ushort* uTn = uT + (size_t)n*PLANE;
    #pragma unroll
    for (int nt=0; nt<2; nt++){
        int s = s0 + nt*16 + l15;
        int y = s/WW, xx = s - y*WW;
        int ys = y+2; if (ys>=HH) ys-=HH;
        int xs = xx-2; if (xs<0) xs+=WW;
        const ushort* up = uTn + ((size_t)ys*WW + xs)*128 + ohalf*64 + quad*4;
        #pragma unroll
        for (int mt=0; mt<4; mt++){
            uint2 uv = *((const uint2*)(up + mt*16));
            float v0 = bflo(uv.x), vv1 = bfhi(uv.x), v2 = bflo(uv.y), v3 = bfhi(uv.y);
            int d = ohalf*64 + mt*16 + quad*4;
            stv(out, ((size_t)n*CC+d+0)*HWS + s, v0  + acc[mt][nt][0]);
            stv(out, ((size_t)n*CC+d+1)*HWS + s, vv1 + acc[mt][nt][1]);
            stv(out, ((size_t)n*CC+d+2)*HWS + s, v2  + acc[mt][nt][2]);
            stv(out, ((size_t)n*CC+d+3)*HWS + s, v3  + acc[mt][nt][3]);
        }
    }
}
__global__ __launch_bounds__(256) void final2_k(const ushort* Bpad, const ushort* coefb,
                                                const ushort* uT, void* out, const int* fl){
    if (*fl) final2_body(Bpad, coefb, uT, (float*)out);
    else     final2_body(Bpad, coefb, uT, (ushort*)out);
}

extern "C" void kernel_launch(void* const* d_in, const int* in_sizes, int n_in,
                              void* d_out, int out_size, void* d_ws, size_t ws_size,
                              hipStream_t stream) {
    const void* x   = d_in[0];
    const void* w3  = d_in[1];
    const void* w4  = d_in[2];
    const void* w9  = d_in[3];
    const void* w10 = d_in[4];
    const void* w15 = d_in[5];

    ushort* t3T  = (ushort*)d_ws;                  // TOT ushorts; reused as uT after dwconvT consumes it
    ushort* uT   = t3T;
    ushort* t4T  = t3T + TOT;                      // TOT ushorts
    ushort* Bpad = t4T + TOT;                      // NB*PLANEP ushorts (26.6MB; alive to the end)
    float*  t5   = (float*)(Bpad + NB*PLANEP);     // 8*16384 floats
    ushort* coefb= (ushort*)(t5 + NB*CC*CC);       // 8*16384
    ushort* Wfb  = coefb + NB*CC*CC;               // 128*224
    ushort* Wpk  = Wfb + CC*224;                   // 128*384
    ushort* Wfa  = Wpk + CC*384;                   // 57344
    float*  wdp  = (float*)(Wfa + 57344);          // 896
    int* flag    = (int*)(wdp + 896);

    detect_k<<<1, 256, 0, stream>>>((const ushort*)x, flag);
    hipMemsetAsync(t5, 0, NB*CC*CC*sizeof(float), stream);

    wpack_k  <<<192, 256, 0, stream>>>(w3, Wpk, flag);
    fusew_k  <<<112, 256, 0, stream>>>(w10, w15, Wfb, flag);
    wfapack_k<<<224, 256, 0, stream>>>(Wfb, Wfa);
    wdpack_k <<<4,   256, 0, stream>>>(w4, wdp, flag);
    bpad_k   <<<dim3(HH,NB), 256, 0, stream>>>(x, Bpad, flag);
    conv3mm_k<<<dim3(196,NB), 256, 0, stream>>>(Bpad, Wpk, t3T);
    dwconvT_k<<<dim3(HH,NB), 256, 0, stream>>>(t3T, wdp, t4T);
    t5mm_k   <<<dim3(98,NB), 256, 0, stream>>>(x, t5, flag);
    coefb_k  <<<NB*CC*CC/256, 256, 0, stream>>>(w9, t5, coefb, flag);
    t15v6_k  <<<dim3(224,NB), 256, 0, stream>>>(t4T, Wfa, uT);   // uT aliases dead t3T
    final2_k <<<dim3(196,NB), 256, 0, stream>>>(Bpad, coefb, uT, d_out, flag);
}

// Round 10
// 290.233 us; speedup vs baseline: 1.0956x; 1.0956x over previous
//
#include <hip/hip_runtime.h>
#include <hip/hip_bf16.h>

#define NB 8
#define CC 128
#define HH 112
#define WW 112
#define HWS (HH*WW)            // 12544
#define PLANE (CC*HWS)         // 1605632
#define TOT (NB*PLANE)         // 12845056
#define XP 116                 // padded x-extent: x+2k, x in [0,112), k in {0,1,2}
#define LROW 130               // LDS row stride in ushorts (65 words == 1 mod 32 -> conflict-free)
#define PLANEP ((size_t)HH*XP*CC)   // per-batch ushorts in Bpad = 1663488
#define NSPLIT 49              // t5 K-split; t5part = 49*8*16384 floats = 25690112 B = exactly 2*TOT bytes

typedef __attribute__((ext_vector_type(8))) short short8v;
typedef __attribute__((ext_vector_type(4))) float float4v;

__device__ __forceinline__ float bflo(unsigned u){ return __uint_as_float(u<<16); }
__device__ __forceinline__ float bfhi(unsigned u){ return __uint_as_float(u & 0xffff0000u); }
__device__ __forceinline__ float ldv(const float* p, size_t i){ return p[i]; }
__device__ __forceinline__ float ldv(const ushort* p, size_t i){ return __uint_as_float(((unsigned)p[i])<<16); }
__device__ __forceinline__ void ld8(const ushort* p, float* v){
    uint4 u0 = *((const uint4*)p);
    v[0]=bflo(u0.x); v[1]=bfhi(u0.x); v[2]=bflo(u0.y); v[3]=bfhi(u0.y);
    v[4]=bflo(u0.z); v[5]=bfhi(u0.z); v[6]=bflo(u0.w); v[7]=bfhi(u0.w);
}
__device__ __forceinline__ void ld8(const float* p, float* v){
    float4 a = *((const float4*)p); float4 b = *((const float4*)(p+4));
    v[0]=a.x; v[1]=a.y; v[2]=a.z; v[3]=a.w; v[4]=b.x; v[5]=b.y; v[6]=b.z; v[7]=b.w;
}
__device__ __forceinline__ void ld4(const float* p, float* v){
    float4 a = *((const float4*)p);
    v[0]=a.x; v[1]=a.y; v[2]=a.z; v[3]=a.w;
}
__device__ __forceinline__ void ld4(const ushort* p, float* v){
    uint2 u = *((const uint2*)p);
    v[0]=bflo(u.x); v[1]=bfhi(u.x); v[2]=bflo(u.y); v[3]=bfhi(u.y);
}
__device__ __forceinline__ ushort f2bf(float f){
    unsigned u = __float_as_uint(f);
    return (ushort)((u + 0x7fffu + ((u>>16)&1u)) >> 16);
}
__device__ __forceinline__ void stv(float* o, size_t i, float v){ o[i]=v; }
__device__ __forceinline__ void stv(ushort* o, size_t i, float v){ o[i]=f2bf(v); }
// fast sigmoid: 1/(1+e^-v) = rcp(1 + 2^(-v*log2e)); ~1ulp fp32 — invisible at bf16 output
__device__ __forceinline__ float fsigmoid(float v){
    float e = __builtin_amdgcn_exp2f(v * -1.44269504f);
    return __builtin_amdgcn_rcpf(1.f + e);
}
// raw bf16 fragment load (no convert round-trip) vs fp32 convert path
__device__ __forceinline__ short8v ldbf(const ushort* p){ return *((const short8v*)p); }
__device__ __forceinline__ short8v ldbf(const float* p){
    float v[8]; ld8(p, v);
    ushort tmp[8];
    #pragma unroll
    for (int j=0;j<8;j++) tmp[j]=f2bf(v[j]);
    return *((const short8v*)tmp);
}

// ---------------- K0: dtype probe. flag=1 -> inputs are fp32 ----------------
__global__ __launch_bounds__(256) void detect_k(const ushort* __restrict__ x, int* __restrict__ flag){
    __shared__ int cnt;
    if (threadIdx.x==0) cnt = 0;
    __syncthreads();
    int bad = 0;
    for (int i = threadIdx.x; i < 2048; i += 256){
        float v = ldv(x, i);
        if (!(v > -1e4f && v < 1e4f)) bad++;
    }
    atomicAdd(&cnt, bad);
    __syncthreads();
    if (threadIdx.x==0) *flag = (cnt > 64) ? 1 : 0;
}

// ---------------- KW1: Wpk[o][kappa=k*128+i] = bf16(w3[o,i,0,k]) ----------------
template<typename ET>
__device__ __forceinline__ void wpack_body(const ET* __restrict__ w3, ushort* __restrict__ Wpk){
    int idx = blockIdx.x*256 + threadIdx.x;
    if (idx < CC*384){
        int o = idx/384, kap = idx - o*384;
        int k = kap>>7, i = kap&127;
        Wpk[idx] = f2bf(ldv(w3, (o*128+i)*3 + k));
    }
}
__global__ __launch_bounds__(256) void wpack_k(const void* w3, ushort* Wpk, const int* fl){
    if (*fl) wpack_body((const float*)w3, Wpk); else wpack_body((const ushort*)w3, Wpk);
}

// ---------------- KB: Bpad[n][y][xp][i] = bf16(silu(x)[i, y, xp-2]), zeros at xp in {0,1,114,115} ----------
template<typename ET>
__device__ __forceinline__ void bpad_body(const ET* __restrict__ x, ushort* __restrict__ Bpad){
    int y = blockIdx.x, n = blockIdx.y;
    __shared__ ushort px[XP*LROW];
    const ET* xb = x + (size_t)n*PLANE + y*WW;
    for (int idx=threadIdx.x; idx<CC*28; idx+=256){      // x4-vectorized global reads
        int i = idx/28, xq = (idx - i*28)*4;
        float v[4]; ld4(xb + (size_t)i*HWS + xq, v);
        #pragma unroll
        for (int d=0;d<4;d++){
            float vv = v[d];
            px[(xq+d+2)*LROW + i] = f2bf(vv * fsigmoid(vv));
        }
    }
    for (int idx=threadIdx.x; idx<4*CC; idx+=256){
        int j = idx >> 7, i = idx & 127;
        int xp = (j<2) ? j : j+112;               // 0,1,114,115
        px[xp*LROW + i] = 0;
    }
    __syncthreads();
    ushort* ob = Bpad + ((size_t)n*HH + y)*XP*CC;
    for (int idx=threadIdx.x; idx<XP*16; idx+=256){
        int xp = idx >> 4, c8 = idx & 15;
        const ushort* pr = px + xp*LROW + c8*8;   // even ushort index -> 4B aligned
        uint4 v;
        v.x = *((const uint*)(pr+0));
        v.y = *((const uint*)(pr+2));
        v.z = *((const uint*)(pr+4));
        v.w = *((const uint*)(pr+6));
        *((uint4*)(ob + (size_t)xp*CC + c8*8)) = v;   // fully coalesced 1KB/wave
    }
}
__global__ __launch_bounds__(256) void bpad_k(const void* x, ushort* Bpad, const int* fl){
    if (*fl) bpad_body((const float*)x, Bpad); else bpad_body((const ushort*)x, Bpad);
}

// ---------------- K2: t3T[n][s][o] = A(128x384) * B(384 x s) — A in LDS, deep B prefetch ----------------
__global__ __launch_bounds__(256) void conv3mm_k(const ushort* __restrict__ Bpad, const ushort* __restrict__ Wpk,
                                                 ushort* __restrict__ t3T){
    int bx = blockIdx.x;        // 0..195
    int n  = blockIdx.y;
    int sbi = bx >> 1, oh = bx & 1;
    int wid = threadIdx.x >> 6, lane = threadIdx.x & 63;
    int l15 = lane & 15, quad = lane >> 4;
    __shared__ ushort Alds[24576];           // 48KB
    {   // cooperative stage: granule g -> (kcmt, l15, quad); 12 x 16B per thread, all in flight
        const int tid = threadIdx.x;
        uint4 tmp[12];
        #pragma unroll
        for (int it=0; it<12; it++){
            int g = it*256 + tid;
            int kcmt = g >> 6, sl = (g>>2)&15, sq = g&3;
            int kc = kcmt >> 2, mt = kcmt & 3;
            tmp[it] = *((const uint4*)(Wpk + (size_t)(oh*64 + mt*16 + sl)*384 + kc*32 + sq*8));
        }
        #pragma unroll
        for (int it=0; it<12; it++){
            int g = it*256 + tid;
            *((uint4*)(Alds + g*8)) = tmp[it];
        }
    }
    __syncthreads();

    int s0 = sbi*128 + wid*32;
    int s1 = s0 + l15, s2 = s1 + 16;
    int y1 = s1/WW, x1 = s1 - y1*WW;
    int y2 = s2/WW, x2 = s2 - y2*WW;
    const ushort* bb = Bpad + (size_t)n*PLANEP;
    const ushort* b1p = bb + ((size_t)y1*XP + x1)*CC + quad*8;
    const ushort* b2p = bb + ((size_t)y2*XP + x2)*CC + quad*8;
    const ushort* al = Alds + l15*32 + quad*8;

    float4v acc[4][2] = {};
    short8v BA[2][4], BB[2][4], a0[4], a1[4];

    auto ldb = [&](int g, short8v (&B)[2][4]){
        #pragma unroll
        for (int m=0;m<4;m++){
            B[0][m] = *((const short8v*)(b1p + g*256 + m*32));
            B[1][m] = *((const short8v*)(b2p + g*256 + m*32));
        }
    };
    auto lda = [&](int kc, short8v (&dst)[4]){
        #pragma unroll
        for (int mt=0;mt<4;mt++) dst[mt] = *((const short8v*)(al + (kc*4+mt)*512));
    };
    auto step = [&](const short8v (&a)[4], const short8v (&B)[2][4], int m){
        #pragma unroll
        for (int mt=0;mt<4;mt++){
            acc[mt][0] = __builtin_amdgcn_mfma_f32_16x16x32_bf16(a[mt], B[0][m], acc[mt][0],0,0,0);
            acc[mt][1] = __builtin_amdgcn_mfma_f32_16x16x32_bf16(a[mt], B[1][m], acc[mt][1],0,0,0);
        }
    };

    ldb(0, BA); lda(0, a0);
    ldb(1, BB);
    lda(1, a1);  step(a0, BA, 0);   // kc0
    lda(2, a0);  step(a1, BA, 1);   // kc1
    lda(3, a1);  step(a0, BA, 2);   // kc2
    lda(4, a0);  step(a1, BA, 3);   // kc3
    ldb(2, BA);                     // region 2 (BA free)
    lda(5, a1);  step(a0, BB, 0);   // kc4
    lda(6, a0);  step(a1, BB, 1);   // kc5
    lda(7, a1);  step(a0, BB, 2);   // kc6
    lda(8, a0);  step(a1, BB, 3);   // kc7
    lda(9, a1);  step(a0, BA, 0);   // kc8
    lda(10, a0); step(a1, BA, 1);   // kc9
    lda(11, a1); step(a0, BA, 2);   // kc10
                 step(a1, BA, 3);   // kc11

    ushort* tb = t3T + (size_t)n*PLANE;
    #pragma unroll
    for (int nt=0; nt<2; nt++){
        int s = s0 + nt*16 + l15;
        ushort* rowp = tb + (size_t)s*128 + oh*64 + quad*4;
        #pragma unroll
        for (int mt=0; mt<4; mt++){
            ushort4 v;
            v.x = f2bf(acc[mt][nt][0]); v.y = f2bf(acc[mt][nt][1]);
            v.z = f2bf(acc[mt][nt][2]); v.w = f2bf(acc[mt][nt][3]);
            *((ushort4*)(rowp + mt*16)) = v;
        }
    }
}

// ---------------- KWD: wdp[k*128+c] = w4[c,k] (fp32) ----------------
template<typename ET>
__device__ __forceinline__ void wdpack_body(const ET* __restrict__ w4, float* __restrict__ wdp){
    int idx = blockIdx.x*256 + threadIdx.x;
    if (idx < 896){ int k = idx >> 7, c = idx & 127; wdp[idx] = ldv(w4, c*7 + k); }
}
__global__ __launch_bounds__(256) void wdpack_k(const void* w4, float* wdp, const int* fl){
    if (*fl) wdpack_body((const float*)w4, wdp); else wdpack_body((const ushort*)w4, wdp);
}

// ---------------- K3: depthwise conv(7,1) dil=(3,1) pad=(9,0) on transposed layout, LDS-free ----------------
__global__ __launch_bounds__(256) void dwconvT_k(const ushort* __restrict__ t3T, const float* __restrict__ wdp,
                                                 ushort* __restrict__ t4T){
    int by = blockIdx.x, n = blockIdx.y;
    int y = (by>>3) + (by&7)*14;   // XCD-contiguous y chunks
    const ushort* tb = t3T + (size_t)n*PLANE;
    ushort* ob = t4T + (size_t)n*PLANE + (size_t)y*WW*128;
    for (int it = threadIdx.x; it < WW*16; it += 256){
        int c8 = it & 15, x = it >> 4;
        int coff = c8*8;
        float acc8[8] = {0.f,0.f,0.f,0.f,0.f,0.f,0.f,0.f};
        #pragma unroll
        for (int k=0;k<7;k++){
            int row = y - 9 + 3*k;
            if (row < 0 || row >= HH) continue;
            float v[8]; ld8(tb + ((size_t)row*WW + x)*128 + coff, v);
            const float* wp = wdp + k*128 + coff;
            #pragma unroll
            for (int j=0;j<8;j++) acc8[j] = fmaf(wp[j], v[j], acc8[j]);
        }
        ushort tmp[8];
        #pragma unroll
        for (int j=0;j<8;j++) tmp[j] = f2bf(acc8[j]);
        *((short8v*)(ob + (size_t)x*128 + coff)) = *((const short8v*)tmp);
    }
}

// ---------------- KW2: Wfb[o][cl*7+k] = bf16(w15[o, cl*7+k] * w10[32g+cl, k]) ----------------
template<typename ET>
__device__ __forceinline__ void fusew_body(const ET* __restrict__ w10, const ET* __restrict__ w15,
                                           ushort* __restrict__ Wfb){
    int idx = blockIdx.x*256+threadIdx.x;
    if (idx < CC*224){
        int o = idx / 224, r = idx - o*224;
        int g = o >> 5;
        int cl = r/7, k = r - cl*7;
        int c = g*32 + cl;
        Wfb[idx] = f2bf(ldv(w15, o*224 + r) * ldv(w10, c*7+k));
    }
}
__global__ __launch_bounds__(256) void fusew_k(const void* w10, const void* w15, ushort* Wfb, const int* fl){
    if (*fl) fusew_body((const float*)w10, (const float*)w15, Wfb);
    else     fusew_body((const ushort*)w10, (const ushort*)w15, Wfb);
}

// ---------------- KWA: Wfa fragment pack. A[w][k][q][mt][l15][j] over c'-aligned 32-blocks ----------------
__global__ __launch_bounds__(256) void wfapack_k(const ushort* __restrict__ Wfb, ushort* __restrict__ Wfa){
    int idx = blockIdx.x*256 + threadIdx.x;   // 4*7*2*2*16*32 = 57344
    if (idx >= 57344) return;
    int j   = idx & 31;
    int l15 = (idx >> 5) & 15;
    int mt  = (idx >> 9) & 1;
    int q   = (idx >> 10) & 1;
    int k   = (idx >> 11) % 7;
    int w   = idx / 14336;
    int o = w*32 + mt*16 + l15;
    int cl = -1;
    if (q==1){ if (j < 30) cl = j + 2; }
    else     { if (j >= 30) cl = j - 30; }
    Wfa[idx] = (cl >= 0) ? Wfb[o*224 + cl*7 + k] : (ushort)0;
}

// ---------------- K6 v6: uT[n, y, x, o] = sum_k Wfa_k * t4T[n, y+2k-6, x, :] ----------------
// DMA pipeline: global_load_lds (16B) direct into 3 rotating LDS buffers, counted vmcnt.
template<int ST0, int NST>
__device__ __forceinline__ void t15_body_v6(const ushort* __restrict__ tbase, const ushort* __restrict__ Wfa,
                                            ushort* __restrict__ urow, int y, int w, int l15, int quad,
                                            ushort* lds){
    int qlo = (w+3)&3;
    int tid = threadIdx.x;
    float4v acc[NST][2] = {};
    int klo = (y >= 6) ? 0 : ((7 - y) >> 1);
    int khi = min(6, (117 - y) >> 1);
    int nk = khi - klo;              // >= 3 always

    const int swz = (tid>>4)&7;      // pi xor mask (depends only on tid bits 4..6)
    const int wbase = tid & ~63;     // wid*64: wave-uniform granule base within a j-chunk

    auto dma_row = [&](int k, int bufi){
        const ushort* rs = tbase + ((size_t)(y + 2*k - 6)*WW + ST0*16)*128;
        #pragma unroll
        for (int j=0;j<NST;j++){
            int g  = j*256 + tid;
            int gs = g ^ swz;                                  // pre-swizzled source granule
            const ushort* gp = rs + (size_t)gs*8;              // per-lane global addr
            ushort* lp = lds + (size_t)bufi*8192 + (size_t)(j*256 + wbase)*8;  // wave-uniform LDS base
            __builtin_amdgcn_global_load_lds((const __attribute__((address_space(1))) void*)gp,
                                             (__attribute__((address_space(3))) void*)lp, 16, 0, 0);
        }
    };
    auto issueA = [&](int k, short8v (&A)[4]){
        const ushort* af = Wfa + (w*7 + k)*2048 + l15*32 + quad*8;
        A[0] = *((const short8v*)(af));
        A[1] = *((const short8v*)(af + 512));
        A[2] = *((const short8v*)(af + 1024));
        A[3] = *((const short8v*)(af + 1536));
    };
    auto domm = [&](int bufi, const short8v (&A)[4]){
        const ushort* lb = lds + bufi*8192;
        #pragma unroll
        for (int st=0; st<NST; st++){
            int xl = st*16 + l15;
            int g0 = xl*16 + qlo*4 + quad;  g0 ^= (g0>>4)&7;
            int g1 = xl*16 + w*4   + quad;  g1 ^= (g1>>4)&7;
            short8v B0 = *((const short8v*)(lb + g0*8));
            short8v B1 = *((const short8v*)(lb + g1*8));
            acc[st][0] = __builtin_amdgcn_mfma_f32_16x16x32_bf16(A[0], B0, acc[st][0], 0,0,0);
            acc[st][1] = __builtin_amdgcn_mfma_f32_16x16x32_bf16(A[1], B0, acc[st][1], 0,0,0);
            acc[st][0] = __builtin_amdgcn_mfma_f32_16x16x32_bf16(A[2], B1, acc[st][0], 0,0,0);
            acc[st][1] = __builtin_amdgcn_mfma_f32_16x16x32_bf16(A[3], B1, acc[st][1], 0,0,0);
        }
    };
    auto iter = [&](int i, short8v (&Acur)[4], short8v (&Anx)[4]){
        // steady: rows i+1 (NST) + A (4) are the only ops newer than row i's DMA
        if (i+2 <= nk){
            if constexpr (NST==4) asm volatile("s_waitcnt vmcnt(8)" ::: "memory");
            else                  asm volatile("s_waitcnt vmcnt(7)" ::: "memory");
        } else {
            asm volatile("s_waitcnt vmcnt(0)" ::: "memory");
        }
        __builtin_amdgcn_s_barrier();
        __builtin_amdgcn_sched_barrier(0);
        if (i+1 <= nk) issueA(klo+i+1, Anx);
        if (i+2 <= nk) dma_row(klo+i+2, (i+2)%3);   // buffer last read at iter i-1; safe after this barrier
        domm(i%3, Acur);
    };

    short8v A0[4], A1[4];
    // prolog: rows klo, klo+1 in flight; A(klo) issued last
    dma_row(klo,   0);
    dma_row(klo+1, 1);
    issueA(klo, A0);

    for (int i=0; i<=nk; i+=2){
        iter(i, A0, A1);
        if (i+1 <= nk) iter(i+1, A1, A0);
    }

    // transposed store: uT[(y*WW + s)*128 + o] — wave w fills its 64B d-chunk of each 256B row
    #pragma unroll
    for (int st=0; st<NST; st++){
        int s = (ST0 + st)*16 + l15;
        ushort* p = urow + (size_t)s*128 + w*32 + quad*4;
        #pragma unroll
        for (int mt=0; mt<2; mt++){
            ushort4 v;
            v.x = f2bf(acc[st][mt][0]); v.y = f2bf(acc[st][mt][1]);
            v.z = f2bf(acc[st][mt][2]); v.w = f2bf(acc[st][mt][3]);
            *((ushort4*)(p + mt*16)) = v;
        }
    }
}
__global__ __launch_bounds__(256) void t15v6_k(const ushort* __restrict__ t4T, const ushort* __restrict__ Wfa,
                                               ushort* __restrict__ uT){
    __shared__ ushort lds[3*8192];     // 48KB: 3 x 16KB row-slice buffers
    int bx = blockIdx.x, n = blockIdx.y;   // bx in [0, 224)
    int xh = bx & 1, byi = bx >> 1;
    int y = (byi>>3) + (byi&7)*14;         // XCD-contiguous y chunks; x-halves paired
    int w = threadIdx.x >> 6, lane = threadIdx.x & 63;
    int l15 = lane & 15, quad = lane >> 4;
    const ushort* tbase = t4T + (size_t)n*PLANE;
    ushort* urow = uT + (size_t)n*PLANE + (size_t)y*WW*128;
    if (xh == 0) t15_body_v6<0,4>(tbase, Wfa, urow, y, w, l15, quad, lds);
    else         t15_body_v6<4,3>(tbase, Wfa, urow, y, w, l15, quad, lds);
}

// ---------------- K4 v4: t5part[ks][n][ci][cj] = sum_{s in chunk} sigmoid(x[ci,s]) * x[cj,s] ----------------
// NO atomics: split-K partials written with regular coalesced stores (atomics were the R7-R9
// bottleneck: WRITE_SIZE == #atomics*4B, TCC atomic-throughput-bound). Reduction fused into coefb_k.
// Grid 49x8; raw bf16 B loads; fast sigmoid on A. Wave: 32 ci x 128 cj, acc[2][8].
template<typename ET>
__device__ __forceinline__ void t5mm_body(const ET* __restrict__ x, float* __restrict__ t5part){
    int ks = blockIdx.x, n = blockIdx.y;    // ks 0..48, 12544 = 49*256
    int wid = threadIdx.x>>6, lane = threadIdx.x&63;
    int l15 = lane&15, quad = lane>>4;
    const ET* xn = x + (size_t)n*PLANE;
    float4v acc[2][8] = {};
    for (int t=0; t<8; t++){
        int sb = ks*256 + t*32 + quad*8;
        short8v afr[2];
        #pragma unroll
        for (int mt=0; mt<2; mt++){
            int row = wid*32 + mt*16 + l15;
            float v[8]; ld8(xn + (size_t)row*HWS + sb, v);
            ushort tmp[8];
            #pragma unroll
            for (int j=0;j<8;j++) tmp[j] = f2bf(fsigmoid(v[j]));
            afr[mt] = *((const short8v*)tmp);
        }
        #pragma unroll
        for (int nt=0; nt<8; nt++){
            int row = nt*16 + l15;
            short8v bfr = ldbf(xn + (size_t)row*HWS + sb);
            acc[0][nt] = __builtin_amdgcn_mfma_f32_16x16x32_bf16(afr[0], bfr, acc[0][nt], 0,0,0);
            acc[1][nt] = __builtin_amdgcn_mfma_f32_16x16x32_bf16(afr[1], bfr, acc[1][nt], 0,0,0);
        }
    }
    float* outp = t5part + (size_t)ks*(NB*16384) + (size_t)n*16384;
    #pragma unroll
    for (int mt=0; mt<2; mt++){
        #pragma unroll
        for (int nt=0; nt<8; nt++){
            #pragma unroll
            for (int r=0; r<4; r++){
                int ci = wid*32 + mt*16 + quad*4 + r;
                int cj = nt*16 + l15;
                outp[ci*128 + cj] = acc[mt][nt][r];
            }
        }
    }
}
__global__ __launch_bounds__(256) void t5mm_k(const void* x, float* t5part, const int* fl){
    if (*fl) t5mm_body((const float*)x, t5part); else t5mm_body((const ushort*)x, t5part);
}

// ---------------- KC v2: coefb[n][d][c] = bf16(w9[c,d] * (sum_ks t5part[ks][n][c][d]) * sc) ----------------
// Input-contiguous thread mapping (d fastest) -> coalesced partial reads; scattered 2B output
// writes land in a 256KB L2-resident region (harmless).
template<typename ET>
__device__ __forceinline__ void coefb_body(const ET* __restrict__ w9, const float* __restrict__ t5part,
                                           ushort* __restrict__ coefb){
    const float sc = 7.89181775e-4f;   // 1/(sqrt(12544)*sqrt(128))
    int idx = blockIdx.x*256 + threadIdx.x;   // over 8*16384, input-contiguous
    int n = idx >> 14, rem = idx & 16383;
    int c = rem >> 7, d = rem & 127;
    const float* p = t5part + (size_t)n*16384 + rem;
    float s = 0.f;
    #pragma unroll 7
    for (int ks=0; ks<NSPLIT; ks++) s += p[(size_t)ks*(NB*16384)];
    coefb[n*16384 + d*128 + c] = f2bf(ldv(w9, c*128 + d) * s * sc);
}
__global__ __launch_bounds__(256) void coefb_k(const void* w9, const float* t5part, ushort* coefb, const int* fl){
    if (*fl) coefb_body((const float*)w9, t5part, coefb); else coefb_body((const ushort*)w9, t5part, coefb);
}

// ---------------- K5 (MFMA): out = uT[shifted] + coefb(128d x 128c) * silu(x)(128c x s) ----------------
// uT is s-major/channel-contiguous: the shifted read is 8B contiguous per (mt,nt) per lane.
template<typename OT>
__device__ __forceinline__ void final2_body(const ushort* __restrict__ Bpad, const ushort* __restrict__ coefb,
                                            const ushort* __restrict__ uT, OT* __restrict__ out){
    int sb = blockIdx.x, n = blockIdx.y;
    int wid = threadIdx.x>>6, lane = threadIdx.x&63;
    int l15 = lane&15, quad = lane>>4;
    int shalf = wid >> 1, ohalf = wid & 1;
    int s0 = sb*64 + shalf*32;
    int s1 = s0 + l15, s2 = s1 + 16;
    int y1 = s1/WW, x1 = s1 - y1*WW;
    int y2 = s2/WW, x2 = s2 - y2*WW;
    const ushort* bb = Bpad + (size_t)n*PLANEP;
    const ushort* b1p = bb + ((size_t)y1*XP + x1 + 2)*CC + quad*8;
    const ushort* b2p = bb + ((size_t)y2*XP + x2 + 2)*CC + quad*8;
    const ushort* abase = coefb + (size_t)n*16384 + (size_t)(ohalf*64 + l15)*128 + quad*8;
    float4v acc[4][2] = {};
    short8v bv0[4], bv1[4], aP[4], aQ[4];
    #pragma unroll
    for (int kc=0;kc<4;kc++){
        bv0[kc] = *((const short8v*)(b1p + kc*32));
        bv1[kc] = *((const short8v*)(b2p + kc*32));
    }
    auto lda = [&](int kc, short8v (&dst)[4]){
        #pragma unroll
        for (int mt=0;mt<4;mt++) dst[mt] = *((const short8v*)(abase + mt*16*128 + kc*32));
    };
    auto step = [&](const short8v (&a)[4], int kc){
        #pragma unroll
        for (int mt=0;mt<4;mt++){
            acc[mt][0] = __builtin_amdgcn_mfma_f32_16x16x32_bf16(a[mt], bv0[kc], acc[mt][0],0,0,0);
            acc[mt][1] = __builtin_amdgcn_mfma_f32_16x16x32_bf16(a[mt], bv1[kc], acc[mt][1],0,0,0);
        }
    };
    lda(0, aP);
    lda(1, aQ); step(aP, 0);
    lda(2, aP); step(aQ, 1);
    lda(3, aQ); step(aP, 2);
                step(aQ, 3);
    const ushort* uTn = uT + (size_t)n*PLANE;
    #pragma unroll
    for (int nt=0; nt<2; nt++){
        int s = s0 + nt*16 + l15;
        int y = s/WW, xx = s - y*WW;
        int ys = y+2; if (ys>=HH) ys-=HH;
        int xs = xx-2; if (xs<0) xs+=WW;
        const ushort* up = uTn + ((size_t)ys*WW + xs)*128 + ohalf*64 + quad*4;
        #pragma unroll
        for (int mt=0; mt<4; mt++){
            uint2 uv = *((const uint2*)(up + mt*16));
            float v0 = bflo(uv.x), vv1 = bfhi(uv.x), v2 = bflo(uv.y), v3 = bfhi(uv.y);
            int d = ohalf*64 + mt*16 + quad*4;
            stv(out, ((size_t)n*CC+d+0)*HWS + s, v0  + acc[mt][nt][0]);
            stv(out, ((size_t)n*CC+d+1)*HWS + s, vv1 + acc[mt][nt][1]);
            stv(out, ((size_t)n*CC+d+2)*HWS + s, v2  + acc[mt][nt][2]);
            stv(out, ((size_t)n*CC+d+3)*HWS + s, v3  + acc[mt][nt][3]);
        }
    }
}
__global__ __launch_bounds__(256) void final2_k(const ushort* Bpad, const ushort* coefb,
                                                const ushort* uT, void* out, const int* fl){
    if (*fl) final2_body(Bpad, coefb, uT, (float*)out);
    else     final2_body(Bpad, coefb, uT, (ushort*)out);
}

extern "C" void kernel_launch(void* const* d_in, const int* in_sizes, int n_in,
                              void* d_out, int out_size, void* d_ws, size_t ws_size,
                              hipStream_t stream) {
    const void* x   = d_in[0];
    const void* w3  = d_in[1];
    const void* w4  = d_in[2];
    const void* w9  = d_in[3];
    const void* w10 = d_in[4];
    const void* w15 = d_in[5];

    ushort* t3T  = (ushort*)d_ws;                  // TOT ushorts; 3 sequential lives:
    float*  t5part = (float*)t3T;                  //   (1) t3T (conv3mm->dwconvT), (2) t5part (t5mm->coefb),
    ushort* uT   = t3T;                            //   (3) uT (t15v6->final2). 49*8*16384*4B == 2*TOT B exactly.
    ushort* t4T  = t3T + TOT;                      // TOT ushorts
    ushort* Bpad = t4T + TOT;                      // NB*PLANEP ushorts (26.6MB; alive to the end)
    ushort* coefb= (ushort*)(Bpad + NB*PLANEP);    // 8*16384
    ushort* Wfb  = coefb + NB*CC*CC;               // 128*224
    ushort* Wpk  = Wfb + CC*224;                   // 128*384
    ushort* Wfa  = Wpk + CC*384;                   // 57344
    float*  wdp  = (float*)(Wfa + 57344);          // 896
    int* flag    = (int*)(wdp + 896);

    detect_k<<<1, 256, 0, stream>>>((const ushort*)x, flag);

    wpack_k  <<<192, 256, 0, stream>>>(w3, Wpk, flag);
    fusew_k  <<<112, 256, 0, stream>>>(w10, w15, Wfb, flag);
    wfapack_k<<<224, 256, 0, stream>>>(Wfb, Wfa);
    wdpack_k <<<4,   256, 0, stream>>>(w4, wdp, flag);
    bpad_k   <<<dim3(HH,NB), 256, 0, stream>>>(x, Bpad, flag);
    conv3mm_k<<<dim3(196,NB), 256, 0, stream>>>(Bpad, Wpk, t3T);
    dwconvT_k<<<dim3(HH,NB), 256, 0, stream>>>(t3T, wdp, t4T);
    t5mm_k   <<<dim3(NSPLIT,NB), 256, 0, stream>>>(x, t5part, flag);   // t5part aliases dead t3T
    coefb_k  <<<NB*CC*CC/256, 256, 0, stream>>>(w9, t5part, coefb, flag);
    t15v6_k  <<<dim3(224,NB), 256, 0, stream>>>(t4T, Wfa, uT);         // uT overwrites consumed t5part
    final2_k <<<dim3(196,NB), 256, 0, stream>>>(Bpad, coefb, uT, d_out, flag);
}

// Round 11
// 288.942 us; speedup vs baseline: 1.1005x; 1.0045x over previous
//
#include <hip/hip_runtime.h>
#include <hip/hip_bf16.h>

#define NB 8
#define CC 128
#define HH 112
#define WW 112
#define HWS (HH*WW)            // 12544
#define PLANE (CC*HWS)         // 1605632
#define TOT (NB*PLANE)         // 12845056
#define XP 116                 // padded x-extent: x+2k, x in [0,112), k in {0,1,2}
#define LROW 130               // LDS row stride in ushorts (65 words == 1 mod 32 -> conflict-free)
#define PLANEP ((size_t)HH*XP*CC)   // per-batch ushorts in Bpad = 1663488
#define NSPLIT 49              // t5 K-split; t5part = 49*8*16384 floats = 25690112 B = exactly 2*TOT bytes

typedef __attribute__((ext_vector_type(8))) short short8v;
typedef __attribute__((ext_vector_type(4))) float float4v;

__device__ __forceinline__ float bflo(unsigned u){ return __uint_as_float(u<<16); }
__device__ __forceinline__ float bfhi(unsigned u){ return __uint_as_float(u & 0xffff0000u); }
__device__ __forceinline__ float ldv(const float* p, size_t i){ return p[i]; }
__device__ __forceinline__ float ldv(const ushort* p, size_t i){ return __uint_as_float(((unsigned)p[i])<<16); }
__device__ __forceinline__ void ld8(const ushort* p, float* v){
    uint4 u0 = *((const uint4*)p);
    v[0]=bflo(u0.x); v[1]=bfhi(u0.x); v[2]=bflo(u0.y); v[3]=bfhi(u0.y);
    v[4]=bflo(u0.z); v[5]=bfhi(u0.z); v[6]=bflo(u0.w); v[7]=bfhi(u0.w);
}
__device__ __forceinline__ void ld8(const float* p, float* v){
    float4 a = *((const float4*)p); float4 b = *((const float4*)(p+4));
    v[0]=a.x; v[1]=a.y; v[2]=a.z; v[3]=a.w; v[4]=b.x; v[5]=b.y; v[6]=b.z; v[7]=b.w;
}
__device__ __forceinline__ void ld4(const float* p, float* v){
    float4 a = *((const float4*)p);
    v[0]=a.x; v[1]=a.y; v[2]=a.z; v[3]=a.w;
}
__device__ __forceinline__ void ld4(const ushort* p, float* v){
    uint2 u = *((const uint2*)p);
    v[0]=bflo(u.x); v[1]=bfhi(u.x); v[2]=bflo(u.y); v[3]=bfhi(u.y);
}
__device__ __forceinline__ ushort f2bf(float f){
    unsigned u = __float_as_uint(f);
    return (ushort)((u + 0x7fffu + ((u>>16)&1u)) >> 16);
}
__device__ __forceinline__ void stv(float* o, size_t i, float v){ o[i]=v; }
__device__ __forceinline__ void stv(ushort* o, size_t i, float v){ o[i]=f2bf(v); }
// fast sigmoid: 1/(1+e^-v) = rcp(1 + 2^(-v*log2e)); ~1ulp fp32 — invisible at bf16 output
__device__ __forceinline__ float fsigmoid(float v){
    float e = __builtin_amdgcn_exp2f(v * -1.44269504f);
    return __builtin_amdgcn_rcpf(1.f + e);
}
// raw bf16 fragment load (no convert round-trip) vs fp32 convert path
__device__ __forceinline__ short8v ldbf(const ushort* p){ return *((const short8v*)p); }
__device__ __forceinline__ short8v ldbf(const float* p){
    float v[8]; ld8(p, v);
    ushort tmp[8];
    #pragma unroll
    for (int j=0;j<8;j++) tmp[j]=f2bf(v[j]);
    return *((const short8v*)tmp);
}

// ---------------- K0: dtype probe. flag=1 -> inputs are fp32 ----------------
__global__ __launch_bounds__(256) void detect_k(const ushort* __restrict__ x, int* __restrict__ flag){
    __shared__ int cnt;
    if (threadIdx.x==0) cnt = 0;
    __syncthreads();
    int bad = 0;
    for (int i = threadIdx.x; i < 2048; i += 256){
        float v = ldv(x, i);
        if (!(v > -1e4f && v < 1e4f)) bad++;
    }
    atomicAdd(&cnt, bad);
    __syncthreads();
    if (threadIdx.x==0) *flag = (cnt > 64) ? 1 : 0;
}

// ---------------- KW1: Wpk[o][kappa=k*128+i] = bf16(w3[o,i,0,k]) ----------------
template<typename ET>
__device__ __forceinline__ void wpack_body(const ET* __restrict__ w3, ushort* __restrict__ Wpk){
    int idx = blockIdx.x*256 + threadIdx.x;
    if (idx < CC*384){
        int o = idx/384, kap = idx - o*384;
        int k = kap>>7, i = kap&127;
        Wpk[idx] = f2bf(ldv(w3, (o*128+i)*3 + k));
    }
}
__global__ __launch_bounds__(256) void wpack_k(const void* w3, ushort* Wpk, const int* fl){
    if (*fl) wpack_body((const float*)w3, Wpk); else wpack_body((const ushort*)w3, Wpk);
}

// ---------------- KB: Bpad[n][y][xp][i] = bf16(silu(x)[i, y, xp-2]), zeros at xp in {0,1,114,115} ----------
template<typename ET>
__device__ __forceinline__ void bpad_body(const ET* __restrict__ x, ushort* __restrict__ Bpad){
    int y = blockIdx.x, n = blockIdx.y;
    __shared__ ushort px[XP*LROW];
    const ET* xb = x + (size_t)n*PLANE + y*WW;
    for (int idx=threadIdx.x; idx<CC*28; idx+=256){      // x4-vectorized global reads
        int i = idx/28, xq = (idx - i*28)*4;
        float v[4]; ld4(xb + (size_t)i*HWS + xq, v);
        #pragma unroll
        for (int d=0;d<4;d++){
            float vv = v[d];
            px[(xq+d+2)*LROW + i] = f2bf(vv * fsigmoid(vv));
        }
    }
    for (int idx=threadIdx.x; idx<4*CC; idx+=256){
        int j = idx >> 7, i = idx & 127;
        int xp = (j<2) ? j : j+112;               // 0,1,114,115
        px[xp*LROW + i] = 0;
    }
    __syncthreads();
    ushort* ob = Bpad + ((size_t)n*HH + y)*XP*CC;
    for (int idx=threadIdx.x; idx<XP*16; idx+=256){
        int xp = idx >> 4, c8 = idx & 15;
        const ushort* pr = px + xp*LROW + c8*8;   // even ushort index -> 4B aligned
        uint4 v;
        v.x = *((const uint*)(pr+0));
        v.y = *((const uint*)(pr+2));
        v.z = *((const uint*)(pr+4));
        v.w = *((const uint*)(pr+6));
        *((uint4*)(ob + (size_t)xp*CC + c8*8)) = v;   // fully coalesced 1KB/wave
    }
}
__global__ __launch_bounds__(256) void bpad_k(const void* x, ushort* Bpad, const int* fl){
    if (*fl) bpad_body((const float*)x, Bpad); else bpad_body((const ushort*)x, Bpad);
}

// ---------------- K2: t3T[n][s][o] = A(128x384) * B(384 x s) — A in LDS, deep B prefetch ----------------
__global__ __launch_bounds__(256) void conv3mm_k(const ushort* __restrict__ Bpad, const ushort* __restrict__ Wpk,
                                                 ushort* __restrict__ t3T){
    int bx = blockIdx.x;        // 0..195
    int n  = blockIdx.y;
    int sbi = bx >> 1, oh = bx & 1;
    int wid = threadIdx.x >> 6, lane = threadIdx.x & 63;
    int l15 = lane & 15, quad = lane >> 4;
    __shared__ ushort Alds[24576];           // 48KB
    {   // cooperative stage: granule g -> (kcmt, l15, quad); 12 x 16B per thread, all in flight
        const int tid = threadIdx.x;
        uint4 tmp[12];
        #pragma unroll
        for (int it=0; it<12; it++){
            int g = it*256 + tid;
            int kcmt = g >> 6, sl = (g>>2)&15, sq = g&3;
            int kc = kcmt >> 2, mt = kcmt & 3;
            tmp[it] = *((const uint4*)(Wpk + (size_t)(oh*64 + mt*16 + sl)*384 + kc*32 + sq*8));
        }
        #pragma unroll
        for (int it=0; it<12; it++){
            int g = it*256 + tid;
            *((uint4*)(Alds + g*8)) = tmp[it];
        }
    }
    __syncthreads();

    int s0 = sbi*128 + wid*32;
    int s1 = s0 + l15, s2 = s1 + 16;
    int y1 = s1/WW, x1 = s1 - y1*WW;
    int y2 = s2/WW, x2 = s2 - y2*WW;
    const ushort* bb = Bpad + (size_t)n*PLANEP;
    const ushort* b1p = bb + ((size_t)y1*XP + x1)*CC + quad*8;
    const ushort* b2p = bb + ((size_t)y2*XP + x2)*CC + quad*8;
    const ushort* al = Alds + l15*32 + quad*8;

    float4v acc[4][2] = {};
    short8v BA[2][4], BB[2][4], a0[4], a1[4];

    auto ldb = [&](int g, short8v (&B)[2][4]){
        #pragma unroll
        for (int m=0;m<4;m++){
            B[0][m] = *((const short8v*)(b1p + g*256 + m*32));
            B[1][m] = *((const short8v*)(b2p + g*256 + m*32));
        }
    };
    auto lda = [&](int kc, short8v (&dst)[4]){
        #pragma unroll
        for (int mt=0;mt<4;mt++) dst[mt] = *((const short8v*)(al + (kc*4+mt)*512));
    };
    auto step = [&](const short8v (&a)[4], const short8v (&B)[2][4], int m){
        #pragma unroll
        for (int mt=0;mt<4;mt++){
            acc[mt][0] = __builtin_amdgcn_mfma_f32_16x16x32_bf16(a[mt], B[0][m], acc[mt][0],0,0,0);
            acc[mt][1] = __builtin_amdgcn_mfma_f32_16x16x32_bf16(a[mt], B[1][m], acc[mt][1],0,0,0);
        }
    };

    ldb(0, BA); lda(0, a0);
    ldb(1, BB);
    lda(1, a1);  step(a0, BA, 0);   // kc0
    lda(2, a0);  step(a1, BA, 1);   // kc1
    lda(3, a1);  step(a0, BA, 2);   // kc2
    lda(4, a0);  step(a1, BA, 3);   // kc3
    ldb(2, BA);                     // region 2 (BA free)
    lda(5, a1);  step(a0, BB, 0);   // kc4
    lda(6, a0);  step(a1, BB, 1);   // kc5
    lda(7, a1);  step(a0, BB, 2);   // kc6
    lda(8, a0);  step(a1, BB, 3);   // kc7
    lda(9, a1);  step(a0, BA, 0);   // kc8
    lda(10, a0); step(a1, BA, 1);   // kc9
    lda(11, a1); step(a0, BA, 2);   // kc10
                 step(a1, BA, 3);   // kc11

    ushort* tb = t3T + (size_t)n*PLANE;
    #pragma unroll
    for (int nt=0; nt<2; nt++){
        int s = s0 + nt*16 + l15;
        ushort* rowp = tb + (size_t)s*128 + oh*64 + quad*4;
        #pragma unroll
        for (int mt=0; mt<4; mt++){
            ushort4 v;
            v.x = f2bf(acc[mt][nt][0]); v.y = f2bf(acc[mt][nt][1]);
            v.z = f2bf(acc[mt][nt][2]); v.w = f2bf(acc[mt][nt][3]);
            *((ushort4*)(rowp + mt*16)) = v;
        }
    }
}

// ---------------- KWD: wdp[k*128+c] = w4[c,k] (fp32) ----------------
template<typename ET>
__device__ __forceinline__ void wdpack_body(const ET* __restrict__ w4, float* __restrict__ wdp){
    int idx = blockIdx.x*256 + threadIdx.x;
    if (idx < 896){ int k = idx >> 7, c = idx & 127; wdp[idx] = ldv(w4, c*7 + k); }
}
__global__ __launch_bounds__(256) void wdpack_k(const void* w4, float* wdp, const int* fl){
    if (*fl) wdpack_body((const float*)w4, wdp); else wdpack_body((const ushort*)w4, wdp);
}

// ---------------- K3: depthwise conv(7,1) dil=(3,1) pad=(9,0) on transposed layout, LDS-free ----------------
__global__ __launch_bounds__(256) void dwconvT_k(const ushort* __restrict__ t3T, const float* __restrict__ wdp,
                                                 ushort* __restrict__ t4T){
    int by = blockIdx.x, n = blockIdx.y;
    int y = (by>>3) + (by&7)*14;   // XCD-contiguous y chunks
    const ushort* tb = t3T + (size_t)n*PLANE;
    ushort* ob = t4T + (size_t)n*PLANE + (size_t)y*WW*128;
    for (int it = threadIdx.x; it < WW*16; it += 256){
        int c8 = it & 15, x = it >> 4;
        int coff = c8*8;
        float acc8[8] = {0.f,0.f,0.f,0.f,0.f,0.f,0.f,0.f};
        #pragma unroll
        for (int k=0;k<7;k++){
            int row = y - 9 + 3*k;
            if (row < 0 || row >= HH) continue;
            float v[8]; ld8(tb + ((size_t)row*WW + x)*128 + coff, v);
            const float* wp = wdp + k*128 + coff;
            #pragma unroll
            for (int j=0;j<8;j++) acc8[j] = fmaf(wp[j], v[j], acc8[j]);
        }
        ushort tmp[8];
        #pragma unroll
        for (int j=0;j<8;j++) tmp[j] = f2bf(acc8[j]);
        *((short8v*)(ob + (size_t)x*128 + coff)) = *((const short8v*)tmp);
    }
}

// ---------------- KW2: Wfb[o][cl*7+k] = bf16(w15[o, cl*7+k] * w10[32g+cl, k]) ----------------
template<typename ET>
__device__ __forceinline__ void fusew_body(const ET* __restrict__ w10, const ET* __restrict__ w15,
                                           ushort* __restrict__ Wfb){
    int idx = blockIdx.x*256+threadIdx.x;
    if (idx < CC*224){
        int o = idx / 224, r = idx - o*224;
        int g = o >> 5;
        int cl = r/7, k = r - cl*7;
        int c = g*32 + cl;
        Wfb[idx] = f2bf(ldv(w15, o*224 + r) * ldv(w10, c*7+k));
    }
}
__global__ __launch_bounds__(256) void fusew_k(const void* w10, const void* w15, ushort* Wfb, const int* fl){
    if (*fl) fusew_body((const float*)w10, (const float*)w15, Wfb);
    else     fusew_body((const ushort*)w10, (const ushort*)w15, Wfb);
}

// ---------------- KWA: Wfa fragment pack. A[w][k][q][mt][l15][j] over c'-aligned 32-blocks ----------------
__global__ __launch_bounds__(256) void wfapack_k(const ushort* __restrict__ Wfb, ushort* __restrict__ Wfa){
    int idx = blockIdx.x*256 + threadIdx.x;   // 4*7*2*2*16*32 = 57344
    if (idx >= 57344) return;
    int j   = idx & 31;
    int l15 = (idx >> 5) & 15;
    int mt  = (idx >> 9) & 1;
    int q   = (idx >> 10) & 1;
    int k   = (idx >> 11) % 7;
    int w   = idx / 14336;
    int o = w*32 + mt*16 + l15;
    int cl = -1;
    if (q==1){ if (j < 30) cl = j + 2; }
    else     { if (j >= 30) cl = j - 30; }
    Wfa[idx] = (cl >= 0) ? Wfb[o*224 + cl*7 + k] : (ushort)0;
}

// ---------------- K6 v6: uT[n, y, x, o] = sum_k Wfa_k * t4T[n, y+2k-6, x, :] ----------------
// DMA pipeline: global_load_lds (16B) direct into 3 rotating LDS buffers, counted vmcnt.
template<int ST0, int NST>
__device__ __forceinline__ void t15_body_v6(const ushort* __restrict__ tbase, const ushort* __restrict__ Wfa,
                                            ushort* __restrict__ urow, int y, int w, int l15, int quad,
                                            ushort* lds){
    int qlo = (w+3)&3;
    int tid = threadIdx.x;
    float4v acc[NST][2] = {};
    int klo = (y >= 6) ? 0 : ((7 - y) >> 1);
    int khi = min(6, (117 - y) >> 1);
    int nk = khi - klo;              // >= 3 always

    const int swz = (tid>>4)&7;      // pi xor mask (depends only on tid bits 4..6)
    const int wbase = tid & ~63;     // wid*64: wave-uniform granule base within a j-chunk

    auto dma_row = [&](int k, int bufi){
        const ushort* rs = tbase + ((size_t)(y + 2*k - 6)*WW + ST0*16)*128;
        #pragma unroll
        for (int j=0;j<NST;j++){
            int g  = j*256 + tid;
            int gs = g ^ swz;                                  // pre-swizzled source granule
            const ushort* gp = rs + (size_t)gs*8;              // per-lane global addr
            ushort* lp = lds + (size_t)bufi*8192 + (size_t)(j*256 + wbase)*8;  // wave-uniform LDS base
            __builtin_amdgcn_global_load_lds((const __attribute__((address_space(1))) void*)gp,
                                             (__attribute__((address_space(3))) void*)lp, 16, 0, 0);
        }
    };
    auto issueA = [&](int k, short8v (&A)[4]){
        const ushort* af = Wfa + (w*7 + k)*2048 + l15*32 + quad*8;
        A[0] = *((const short8v*)(af));
        A[1] = *((const short8v*)(af + 512));
        A[2] = *((const short8v*)(af + 1024));
        A[3] = *((const short8v*)(af + 1536));
    };
    auto domm = [&](int bufi, const short8v (&A)[4]){
        const ushort* lb = lds + bufi*8192;
        #pragma unroll
        for (int st=0; st<NST; st++){
            int xl = st*16 + l15;
            int g0 = xl*16 + qlo*4 + quad;  g0 ^= (g0>>4)&7;
            int g1 = xl*16 + w*4   + quad;  g1 ^= (g1>>4)&7;
            short8v B0 = *((const short8v*)(lb + g0*8));
            short8v B1 = *((const short8v*)(lb + g1*8));
            acc[st][0] = __builtin_amdgcn_mfma_f32_16x16x32_bf16(A[0], B0, acc[st][0], 0,0,0);
            acc[st][1] = __builtin_amdgcn_mfma_f32_16x16x32_bf16(A[1], B0, acc[st][1], 0,0,0);
            acc[st][0] = __builtin_amdgcn_mfma_f32_16x16x32_bf16(A[2], B1, acc[st][0], 0,0,0);
            acc[st][1] = __builtin_amdgcn_mfma_f32_16x16x32_bf16(A[3], B1, acc[st][1], 0,0,0);
        }
    };
    auto iter = [&](int i, short8v (&Acur)[4], short8v (&Anx)[4]){
        // steady: rows i+1 (NST) + A (4) are the only ops newer than row i's DMA
        if (i+2 <= nk){
            if constexpr (NST==4) asm volatile("s_waitcnt vmcnt(8)" ::: "memory");
            else                  asm volatile("s_waitcnt vmcnt(7)" ::: "memory");
        } else {
            asm volatile("s_waitcnt vmcnt(0)" ::: "memory");
        }
        __builtin_amdgcn_s_barrier();
        __builtin_amdgcn_sched_barrier(0);
        if (i+1 <= nk) issueA(klo+i+1, Anx);
        if (i+2 <= nk) dma_row(klo+i+2, (i+2)%3);   // buffer last read at iter i-1; safe after this barrier
        domm(i%3, Acur);
    };

    short8v A0[4], A1[4];
    // prolog: rows klo, klo+1 in flight; A(klo) issued last
    dma_row(klo,   0);
    dma_row(klo+1, 1);
    issueA(klo, A0);

    for (int i=0; i<=nk; i+=2){
        iter(i, A0, A1);
        if (i+1 <= nk) iter(i+1, A1, A0);
    }

    // transposed store: uT[(y*WW + s)*128 + o] — wave w fills its 64B d-chunk of each 256B row
    #pragma unroll
    for (int st=0; st<NST; st++){
        int s = (ST0 + st)*16 + l15;
        ushort* p = urow + (size_t)s*128 + w*32 + quad*4;
        #pragma unroll
        for (int mt=0; mt<2; mt++){
            ushort4 v;
            v.x = f2bf(acc[st][mt][0]); v.y = f2bf(acc[st][mt][1]);
            v.z = f2bf(acc[st][mt][2]); v.w = f2bf(acc[st][mt][3]);
            *((ushort4*)(p + mt*16)) = v;
        }
    }
}
__global__ __launch_bounds__(256) void t15v6_k(const ushort* __restrict__ t4T, const ushort* __restrict__ Wfa,
                                               ushort* __restrict__ uT){
    __shared__ ushort lds[3*8192];     // 48KB: 3 x 16KB row-slice buffers
    int bx = blockIdx.x, n = blockIdx.y;   // bx in [0, 224)
    int xh = bx & 1, byi = bx >> 1;
    int y = (byi>>3) + (byi&7)*14;         // XCD-contiguous y chunks; x-halves paired
    int w = threadIdx.x >> 6, lane = threadIdx.x & 63;
    int l15 = lane & 15, quad = lane >> 4;
    const ushort* tbase = t4T + (size_t)n*PLANE;
    ushort* urow = uT + (size_t)n*PLANE + (size_t)y*WW*128;
    if (xh == 0) t15_body_v6<0,4>(tbase, Wfa, urow, y, w, l15, quad, lds);
    else         t15_body_v6<4,3>(tbase, Wfa, urow, y, w, l15, quad, lds);
}

// ---------------- K4 v5: t5part[ks][n][ci][cj] = sum_{s in 256-chunk} sigmoid(x[ci,s]) * x[cj,s] ----------------
// 512 threads / 8 waves: wave (shalf, wci) covers half the s-chunk (4 t-iters -> half the
// serialized latency chain) x 32 ci. shalf=1 waves dump acc to LDS (stride 129 -> ~conflict-free);
// shalf=0 waves add + single coalesced partial store. Volumes identical to v4; 2x wave parallelism.
template<typename ET>
__device__ __forceinline__ void t5mm_body(const ET* __restrict__ x, float* __restrict__ t5part){
    __shared__ float red[4][32*129];        // 66048 B
    int ks = blockIdx.x, n = blockIdx.y;    // ks 0..48, 12544 = 49*256
    int tid = threadIdx.x;
    int wid = tid>>6, lane = tid&63;
    int l15 = lane&15, quad = lane>>4;
    int wci = wid & 3, shalf = wid >> 2;
    const ET* xn = x + (size_t)n*PLANE;
    float4v acc[2][8] = {};
    for (int t=0; t<4; t++){
        int sb = ks*256 + shalf*128 + t*32 + quad*8;
        short8v afr[2];
        #pragma unroll
        for (int mt=0; mt<2; mt++){
            int row = wci*32 + mt*16 + l15;
            float v[8]; ld8(xn + (size_t)row*HWS + sb, v);
            ushort tmp[8];
            #pragma unroll
            for (int j=0;j<8;j++) tmp[j] = f2bf(fsigmoid(v[j]));
            afr[mt] = *((const short8v*)tmp);
        }
        #pragma unroll
        for (int nt=0; nt<8; nt++){
            int row = nt*16 + l15;
            short8v bfr = ldbf(xn + (size_t)row*HWS + sb);
            acc[0][nt] = __builtin_amdgcn_mfma_f32_16x16x32_bf16(afr[0], bfr, acc[0][nt], 0,0,0);
            acc[1][nt] = __builtin_amdgcn_mfma_f32_16x16x32_bf16(afr[1], bfr, acc[1][nt], 0,0,0);
        }
    }
    if (shalf == 1){
        float* rp = red[wci];
        #pragma unroll
        for (int mt=0; mt<2; mt++)
            #pragma unroll
            for (int nt=0; nt<8; nt++)
                #pragma unroll
                for (int r=0; r<4; r++){
                    int cil = mt*16 + quad*4 + r;
                    int cj  = nt*16 + l15;
                    rp[cil*129 + cj] = acc[mt][nt][r];
                }
    }
    __syncthreads();
    if (shalf == 0){
        const float* rp = red[wci];
        float* outp = t5part + (size_t)ks*(NB*16384) + (size_t)n*16384 + wci*32*128;
        #pragma unroll
        for (int mt=0; mt<2; mt++)
            #pragma unroll
            for (int nt=0; nt<8; nt++)
                #pragma unroll
                for (int r=0; r<4; r++){
                    int cil = mt*16 + quad*4 + r;
                    int cj  = nt*16 + l15;
                    outp[cil*128 + cj] = acc[mt][nt][r] + rp[cil*129 + cj];
                }
    }
}
__global__ __launch_bounds__(512) void t5mm_k(const void* x, float* t5part, const int* fl){
    if (*fl) t5mm_body((const float*)x, t5part); else t5mm_body((const ushort*)x, t5part);
}

// ---------------- KC v2: coefb[n][d][c] = bf16(w9[c,d] * (sum_ks t5part[ks][n][c][d]) * sc) ----------------
template<typename ET>
__device__ __forceinline__ void coefb_body(const ET* __restrict__ w9, const float* __restrict__ t5part,
                                           ushort* __restrict__ coefb){
    const float sc = 7.89181775e-4f;   // 1/(sqrt(12544)*sqrt(128))
    int idx = blockIdx.x*256 + threadIdx.x;   // over 8*16384, input-contiguous
    int n = idx >> 14, rem = idx & 16383;
    int c = rem >> 7, d = rem & 127;
    const float* p = t5part + (size_t)n*16384 + rem;
    float s = 0.f;
    #pragma unroll 7
    for (int ks=0; ks<NSPLIT; ks++) s += p[(size_t)ks*(NB*16384)];
    coefb[n*16384 + d*128 + c] = f2bf(ldv(w9, c*128 + d) * s * sc);
}
__global__ __launch_bounds__(256) void coefb_k(const void* w9, const float* t5part, ushort* coefb, const int* fl){
    if (*fl) coefb_body((const float*)w9, t5part, coefb); else coefb_body((const ushort*)w9, t5part, coefb);
}

// ---------------- K5 (MFMA): out = uT[shifted] + coefb(128d x 128c) * silu(x)(128c x s) ----------------
template<typename OT>
__device__ __forceinline__ void final2_body(const ushort* __restrict__ Bpad, const ushort* __restrict__ coefb,
                                            const ushort* __restrict__ uT, OT* __restrict__ out){
    int sb = blockIdx.x, n = blockIdx.y;
    int wid = threadIdx.x>>6, lane = threadIdx.x&63;
    int l15 = lane&15, quad = lane>>4;
    int shalf = wid >> 1, ohalf = wid & 1;
    int s0 = sb*64 + shalf*32;
    int s1 = s0 + l15, s2 = s1 + 16;
    int y1 = s1/WW, x1 = s1 - y1*WW;
    int y2 = s2/WW, x2 = s2 - y2*WW;
    const ushort* bb = Bpad + (size_t)n*PLANEP;
    const ushort* b1p = bb + ((size_t)y1*XP + x1 + 2)*CC + quad*8;
    const ushort* b2p = bb + ((size_t)y2*XP + x2 + 2)*CC + quad*8;
    const ushort* abase = coefb + (size_t)n*16384 + (size_t)(ohalf*64 + l15)*128 + quad*8;
    float4v acc[4][2] = {};
    short8v bv0[4], bv1[4], aP[4], aQ[4];
    #pragma unroll
    for (int kc=0;kc<4;kc++){
        bv0[kc] = *((const short8v*)(b1p + kc*32));
        bv1[kc] = *((const short8v*)(b2p + kc*32));
    }
    auto lda = [&](int kc, short8v (&dst)[4]){
        #pragma unroll
        for (int mt=0;mt<4;mt++) dst[mt] = *((const short8v*)(abase + mt*16*128 + kc*32));
    };
    auto step = [&](const short8v (&a)[4], int kc){
        #pragma unroll
        for (int mt=0;mt<4;mt++){
            acc[mt][0] = __builtin_amdgcn_mfma_f32_16x16x32_bf16(a[mt], bv0[kc], acc[mt][0],0,0,0);
            acc[mt][1] = __builtin_amdgcn_mfma_f32_16x16x32_bf16(a[mt], bv1[kc], acc[mt][1],0,0,0);
        }
    };
    lda(0, aP);
    lda(1, aQ); step(aP, 0);
    lda(2, aP); step(aQ, 1);
    lda(3, aQ); step(aP, 2);
                step(aQ, 3);
    const ushort* uTn = uT + (size_t)n*PLANE;
    #pragma unroll
    for (int nt=0; nt<2; nt++){
        int s = s0 + nt*16 + l15;
        int y = s/WW, xx = s - y*WW;
        int ys = y+2; if (ys>=HH) ys-=HH;
        int xs = xx-2; if (xs<0) xs+=WW;
        const ushort* up = uTn + ((size_t)ys*WW + xs)*128 + ohalf*64 + quad*4;
        #pragma unroll
        for (int mt=0; mt<4; mt++){
            uint2 uv = *((const uint2*)(up + mt*16));
            float v0 = bflo(uv.x), vv1 = bfhi(uv.x), v2 = bflo(uv.y), v3 = bfhi(uv.y);
            int d = ohalf*64 + mt*16 + quad*4;
            stv(out, ((size_t)n*CC+d+0)*HWS + s, v0  + acc[mt][nt][0]);
            stv(out, ((size_t)n*CC+d+1)*HWS + s, vv1 + acc[mt][nt][1]);
            stv(out, ((size_t)n*CC+d+2)*HWS + s, v2  + acc[mt][nt][2]);
            stv(out, ((size_t)n*CC+d+3)*HWS + s, v3  + acc[mt][nt][3]);
        }
    }
}
__global__ __launch_bounds__(256) void final2_k(const ushort* Bpad, const ushort* coefb,
                                                const ushort* uT, void* out, const int* fl){
    if (*fl) final2_body(Bpad, coefb, uT, (float*)out);
    else     final2_body(Bpad, coefb, uT, (ushort*)out);
}

extern "C" void kernel_launch(void* const* d_in, const int* in_sizes, int n_in,
                              void* d_out, int out_size, void* d_ws, size_t ws_size,
                              hipStream_t stream) {
    const void* x   = d_in[0];
    const void* w3  = d_in[1];
    const void* w4  = d_in[2];
    const void* w9  = d_in[3];
    const void* w10 = d_in[4];
    const void* w15 = d_in[5];

    ushort* t3T  = (ushort*)d_ws;                  // TOT ushorts; 3 sequential lives:
    float*  t5part = (float*)t3T;                  //   (1) t3T (conv3mm->dwconvT), (2) t5part (t5mm->coefb),
    ushort* uT   = t3T;                            //   (3) uT (t15v6->final2). 49*8*16384*4B == 2*TOT B exactly.
    ushort* t4T  = t3T + TOT;                      // TOT ushorts
    ushort* Bpad = t4T + TOT;                      // NB*PLANEP ushorts (26.6MB; alive to the end)
    ushort* coefb= (ushort*)(Bpad + NB*PLANEP);    // 8*16384
    ushort* Wfb  = coefb + NB*CC*CC;               // 128*224
    ushort* Wpk  = Wfb + CC*224;                   // 128*384
    ushort* Wfa  = Wpk + CC*384;                   // 57344
    float*  wdp  = (float*)(Wfa + 57344);          // 896
    int* flag    = (int*)(wdp + 896);

    detect_k<<<1, 256, 0, stream>>>((const ushort*)x, flag);

    wpack_k  <<<192, 256, 0, stream>>>(w3, Wpk, flag);
    fusew_k  <<<112, 256, 0, stream>>>(w10, w15, Wfb, flag);
    wfapack_k<<<224, 256, 0, stream>>>(Wfb, Wfa);
    wdpack_k <<<4,   256, 0, stream>>>(w4, wdp, flag);
    bpad_k   <<<dim3(HH,NB), 256, 0, stream>>>(x, Bpad, flag);
    conv3mm_k<<<dim3(196,NB), 256, 0, stream>>>(Bpad, Wpk, t3T);
    dwconvT_k<<<dim3(HH,NB), 256, 0, stream>>>(t3T, wdp, t4T);
    t5mm_k   <<<dim3(NSPLIT,NB), 512, 0, stream>>>(x, t5part, flag);   // t5part aliases dead t3T
    coefb_k  <<<NB*CC*CC/256, 256, 0, stream>>>(w9, t5part, coefb, flag);
    t15v6_k  <<<dim3(224,NB), 256, 0, stream>>>(t4T, Wfa, uT);         // uT overwrites consumed t5part
    final2_k <<<dim3(196,NB), 256, 0, stream>>>(Bpad, coefb, uT, d_out, flag);
}

// Round 12
// 282.221 us; speedup vs baseline: 1.1267x; 1.0238x over previous
//
#include <hip/hip_runtime.h>
#include <hip/hip_bf16.h>

#define NB 8
#define CC 128
#define HH 112
#define WW 112
#define HWS (HH*WW)            // 12544
#define PLANE (CC*HWS)         // 1605632
#define TOT (NB*PLANE)         // 12845056
#define XP 116                 // padded x-extent: x+2k, x in [0,112), k in {0,1,2}
#define LROW 130               // LDS row stride in ushorts (65 words == 1 mod 32 -> conflict-free)
#define PLANEP ((size_t)HH*XP*CC)   // per-batch ushorts in Bpad = 1663488
#define NSPLIT 49              // t5 K-split; t5part = 49*8*16384 floats = 25690112 B = exactly 2*TOT bytes
#define RSTRIDE 130            // t5 reduce stride in floats: 4*130 % 32 == 8 -> exact 2-way (free)

typedef __attribute__((ext_vector_type(8))) short short8v;
typedef __attribute__((ext_vector_type(4))) float float4v;

__device__ __forceinline__ float bflo(unsigned u){ return __uint_as_float(u<<16); }
__device__ __forceinline__ float bfhi(unsigned u){ return __uint_as_float(u & 0xffff0000u); }
__device__ __forceinline__ float ldv(const float* p, size_t i){ return p[i]; }
__device__ __forceinline__ float ldv(const ushort* p, size_t i){ return __uint_as_float(((unsigned)p[i])<<16); }
__device__ __forceinline__ void ld8(const ushort* p, float* v){
    uint4 u0 = *((const uint4*)p);
    v[0]=bflo(u0.x); v[1]=bfhi(u0.x); v[2]=bflo(u0.y); v[3]=bfhi(u0.y);
    v[4]=bflo(u0.z); v[5]=bfhi(u0.z); v[6]=bflo(u0.w); v[7]=bfhi(u0.w);
}
__device__ __forceinline__ void ld8(const float* p, float* v){
    float4 a = *((const float4*)p); float4 b = *((const float4*)(p+4));
    v[0]=a.x; v[1]=a.y; v[2]=a.z; v[3]=a.w; v[4]=b.x; v[5]=b.y; v[6]=b.z; v[7]=b.w;
}
__device__ __forceinline__ void ld4(const float* p, float* v){
    float4 a = *((const float4*)p);
    v[0]=a.x; v[1]=a.y; v[2]=a.z; v[3]=a.w;
}
__device__ __forceinline__ void ld4(const ushort* p, float* v){
    uint2 u = *((const uint2*)p);
    v[0]=bflo(u.x); v[1]=bfhi(u.x); v[2]=bflo(u.y); v[3]=bfhi(u.y);
}
__device__ __forceinline__ ushort f2bf(float f){
    unsigned u = __float_as_uint(f);
    return (ushort)((u + 0x7fffu + ((u>>16)&1u)) >> 16);
}
__device__ __forceinline__ void stv(float* o, size_t i, float v){ o[i]=v; }
__device__ __forceinline__ void stv(ushort* o, size_t i, float v){ o[i]=f2bf(v); }
// fast sigmoid: 1/(1+e^-v) = rcp(1 + 2^(-v*log2e)); ~1ulp fp32 — invisible at bf16 output
__device__ __forceinline__ float fsigmoid(float v){
    float e = __builtin_amdgcn_exp2f(v * -1.44269504f);
    return __builtin_amdgcn_rcpf(1.f + e);
}
// raw bf16 fragment load (no convert round-trip) vs fp32 convert path
__device__ __forceinline__ short8v ldbf(const ushort* p){ return *((const short8v*)p); }
__device__ __forceinline__ short8v ldbf(const float* p){
    float v[8]; ld8(p, v);
    ushort tmp[8];
    #pragma unroll
    for (int j=0;j<8;j++) tmp[j]=f2bf(v[j]);
    return *((const short8v*)tmp);
}

// ---------------- K0: dtype probe. flag=1 -> inputs are fp32 ----------------
__global__ __launch_bounds__(256) void detect_k(const ushort* __restrict__ x, int* __restrict__ flag){
    __shared__ int cnt;
    if (threadIdx.x==0) cnt = 0;
    __syncthreads();
    int bad = 0;
    for (int i = threadIdx.x; i < 2048; i += 256){
        float v = ldv(x, i);
        if (!(v > -1e4f && v < 1e4f)) bad++;
    }
    atomicAdd(&cnt, bad);
    __syncthreads();
    if (threadIdx.x==0) *flag = (cnt > 64) ? 1 : 0;
}

// ---------------- KW1: Wpk[o][kappa=k*128+i] = bf16(w3[o,i,0,k]) ----------------
template<typename ET>
__device__ __forceinline__ void wpack_body(const ET* __restrict__ w3, ushort* __restrict__ Wpk){
    int idx = blockIdx.x*256 + threadIdx.x;
    if (idx < CC*384){
        int o = idx/384, kap = idx - o*384;
        int k = kap>>7, i = kap&127;
        Wpk[idx] = f2bf(ldv(w3, (o*128+i)*3 + k));
    }
}
__global__ __launch_bounds__(256) void wpack_k(const void* w3, ushort* Wpk, const int* fl){
    if (*fl) wpack_body((const float*)w3, Wpk); else wpack_body((const ushort*)w3, Wpk);
}

// ---------------- KB: Bpad[n][y][xp][i] = bf16(silu(x)[i, y, xp-2]), zeros at xp in {0,1,114,115} ----------
// __shared__ hoisted to the __global__ wrapper: template-body statics get DUPLICATED per
// instantiation (fp32+bf16 paths co-compiled) -> 2x LDS -> halved occupancy (R11 lesson).
template<typename ET>
__device__ __forceinline__ void bpad_body(const ET* __restrict__ x, ushort* __restrict__ Bpad, ushort* px){
    int y = blockIdx.x, n = blockIdx.y;
    const ET* xb = x + (size_t)n*PLANE + y*WW;
    for (int idx=threadIdx.x; idx<CC*28; idx+=256){      // x4-vectorized global reads
        int i = idx/28, xq = (idx - i*28)*4;
        float v[4]; ld4(xb + (size_t)i*HWS + xq, v);
        #pragma unroll
        for (int d=0;d<4;d++){
            float vv = v[d];
            px[(xq+d+2)*LROW + i] = f2bf(vv * fsigmoid(vv));
        }
    }
    for (int idx=threadIdx.x; idx<4*CC; idx+=256){
        int j = idx >> 7, i = idx & 127;
        int xp = (j<2) ? j : j+112;               // 0,1,114,115
        px[xp*LROW + i] = 0;
    }
    __syncthreads();
    ushort* ob = Bpad + ((size_t)n*HH + y)*XP*CC;
    for (int idx=threadIdx.x; idx<XP*16; idx+=256){
        int xp = idx >> 4, c8 = idx & 15;
        const ushort* pr = px + xp*LROW + c8*8;   // even ushort index -> 4B aligned
        uint4 v;
        v.x = *((const uint*)(pr+0));
        v.y = *((const uint*)(pr+2));
        v.z = *((const uint*)(pr+4));
        v.w = *((const uint*)(pr+6));
        *((uint4*)(ob + (size_t)xp*CC + c8*8)) = v;   // fully coalesced 1KB/wave
    }
}
__global__ __launch_bounds__(256) void bpad_k(const void* x, ushort* Bpad, const int* fl){
    __shared__ ushort px[XP*LROW];                 // 30160 B, single allocation
    if (*fl) bpad_body((const float*)x, Bpad, px); else bpad_body((const ushort*)x, Bpad, px);
}

// ---------------- K2: t3T[n][s][o] = A(128x384) * B(384 x s) — A in LDS, deep B prefetch ----------------
__global__ __launch_bounds__(256) void conv3mm_k(const ushort* __restrict__ Bpad, const ushort* __restrict__ Wpk,
                                                 ushort* __restrict__ t3T){
    int bx = blockIdx.x;        // 0..195
    int n  = blockIdx.y;
    int sbi = bx >> 1, oh = bx & 1;
    int wid = threadIdx.x >> 6, lane = threadIdx.x & 63;
    int l15 = lane & 15, quad = lane >> 4;
    __shared__ ushort Alds[24576];           // 48KB
    {   // cooperative stage: granule g -> (kcmt, l15, quad); 12 x 16B per thread, all in flight
        const int tid = threadIdx.x;
        uint4 tmp[12];
        #pragma unroll
        for (int it=0; it<12; it++){
            int g = it*256 + tid;
            int kcmt = g >> 6, sl = (g>>2)&15, sq = g&3;
            int kc = kcmt >> 2, mt = kcmt & 3;
            tmp[it] = *((const uint4*)(Wpk + (size_t)(oh*64 + mt*16 + sl)*384 + kc*32 + sq*8));
        }
        #pragma unroll
        for (int it=0; it<12; it++){
            int g = it*256 + tid;
            *((uint4*)(Alds + g*8)) = tmp[it];
        }
    }
    __syncthreads();

    int s0 = sbi*128 + wid*32;
    int s1 = s0 + l15, s2 = s1 + 16;
    int y1 = s1/WW, x1 = s1 - y1*WW;
    int y2 = s2/WW, x2 = s2 - y2*WW;
    const ushort* bb = Bpad + (size_t)n*PLANEP;
    const ushort* b1p = bb + ((size_t)y1*XP + x1)*CC + quad*8;
    const ushort* b2p = bb + ((size_t)y2*XP + x2)*CC + quad*8;
    const ushort* al = Alds + l15*32 + quad*8;

    float4v acc[4][2] = {};
    short8v BA[2][4], BB[2][4], a0[4], a1[4];

    auto ldb = [&](int g, short8v (&B)[2][4]){
        #pragma unroll
        for (int m=0;m<4;m++){
            B[0][m] = *((const short8v*)(b1p + g*256 + m*32));
            B[1][m] = *((const short8v*)(b2p + g*256 + m*32));
        }
    };
    auto lda = [&](int kc, short8v (&dst)[4]){
        #pragma unroll
        for (int mt=0;mt<4;mt++) dst[mt] = *((const short8v*)(al + (kc*4+mt)*512));
    };
    auto step = [&](const short8v (&a)[4], const short8v (&B)[2][4], int m){
        #pragma unroll
        for (int mt=0;mt<4;mt++){
            acc[mt][0] = __builtin_amdgcn_mfma_f32_16x16x32_bf16(a[mt], B[0][m], acc[mt][0],0,0,0);
            acc[mt][1] = __builtin_amdgcn_mfma_f32_16x16x32_bf16(a[mt], B[1][m], acc[mt][1],0,0,0);
        }
    };

    ldb(0, BA); lda(0, a0);
    ldb(1, BB);
    lda(1, a1);  step(a0, BA, 0);   // kc0
    lda(2, a0);  step(a1, BA, 1);   // kc1
    lda(3, a1);  step(a0, BA, 2);   // kc2
    lda(4, a0);  step(a1, BA, 3);   // kc3
    ldb(2, BA);                     // region 2 (BA free)
    lda(5, a1);  step(a0, BB, 0);   // kc4
    lda(6, a0);  step(a1, BB, 1);   // kc5
    lda(7, a1);  step(a0, BB, 2);   // kc6
    lda(8, a0);  step(a1, BB, 3);   // kc7
    lda(9, a1);  step(a0, BA, 0);   // kc8
    lda(10, a0); step(a1, BA, 1);   // kc9
    lda(11, a1); step(a0, BA, 2);   // kc10
                 step(a1, BA, 3);   // kc11

    ushort* tb = t3T + (size_t)n*PLANE;
    #pragma unroll
    for (int nt=0; nt<2; nt++){
        int s = s0 + nt*16 + l15;
        ushort* rowp = tb + (size_t)s*128 + oh*64 + quad*4;
        #pragma unroll
        for (int mt=0; mt<4; mt++){
            ushort4 v;
            v.x = f2bf(acc[mt][nt][0]); v.y = f2bf(acc[mt][nt][1]);
            v.z = f2bf(acc[mt][nt][2]); v.w = f2bf(acc[mt][nt][3]);
            *((ushort4*)(rowp + mt*16)) = v;
        }
    }
}

// ---------------- KWD: wdp[k*128+c] = w4[c,k] (fp32) ----------------
template<typename ET>
__device__ __forceinline__ void wdpack_body(const ET* __restrict__ w4, float* __restrict__ wdp){
    int idx = blockIdx.x*256 + threadIdx.x;
    if (idx < 896){ int k = idx >> 7, c = idx & 127; wdp[idx] = ldv(w4, c*7 + k); }
}
__global__ __launch_bounds__(256) void wdpack_k(const void* w4, float* wdp, const int* fl){
    if (*fl) wdpack_body((const float*)w4, wdp); else wdpack_body((const ushort*)w4, wdp);
}

// ---------------- K3: depthwise conv(7,1) dil=(3,1) pad=(9,0) on transposed layout, LDS-free ----------------
__global__ __launch_bounds__(256) void dwconvT_k(const ushort* __restrict__ t3T, const float* __restrict__ wdp,
                                                 ushort* __restrict__ t4T){
    int by = blockIdx.x, n = blockIdx.y;
    int y = (by>>3) + (by&7)*14;   // XCD-contiguous y chunks
    const ushort* tb = t3T + (size_t)n*PLANE;
    ushort* ob = t4T + (size_t)n*PLANE + (size_t)y*WW*128;
    for (int it = threadIdx.x; it < WW*16; it += 256){
        int c8 = it & 15, x = it >> 4;
        int coff = c8*8;
        float acc8[8] = {0.f,0.f,0.f,0.f,0.f,0.f,0.f,0.f};
        #pragma unroll
        for (int k=0;k<7;k++){
            int row = y - 9 + 3*k;
            if (row < 0 || row >= HH) continue;
            float v[8]; ld8(tb + ((size_t)row*WW + x)*128 + coff, v);
            const float* wp = wdp + k*128 + coff;
            #pragma unroll
            for (int j=0;j<8;j++) acc8[j] = fmaf(wp[j], v[j], acc8[j]);
        }
        ushort tmp[8];
        #pragma unroll
        for (int j=0;j<8;j++) tmp[j] = f2bf(acc8[j]);
        *((short8v*)(ob + (size_t)x*128 + coff)) = *((const short8v*)tmp);
    }
}

// ---------------- KW2: Wfb[o][cl*7+k] = bf16(w15[o, cl*7+k] * w10[32g+cl, k]) ----------------
template<typename ET>
__device__ __forceinline__ void fusew_body(const ET* __restrict__ w10, const ET* __restrict__ w15,
                                           ushort* __restrict__ Wfb){
    int idx = blockIdx.x*256+threadIdx.x;
    if (idx < CC*224){
        int o = idx / 224, r = idx - o*224;
        int g = o >> 5;
        int cl = r/7, k = r - cl*7;
        int c = g*32 + cl;
        Wfb[idx] = f2bf(ldv(w15, o*224 + r) * ldv(w10, c*7+k));
    }
}
__global__ __launch_bounds__(256) void fusew_k(const void* w10, const void* w15, ushort* Wfb, const int* fl){
    if (*fl) fusew_body((const float*)w10, (const float*)w15, Wfb);
    else     fusew_body((const ushort*)w10, (const ushort*)w15, Wfb);
}

// ---------------- KWA: Wfa fragment pack. A[w][k][q][mt][l15][j] over c'-aligned 32-blocks ----------------
__global__ __launch_bounds__(256) void wfapack_k(const ushort* __restrict__ Wfb, ushort* __restrict__ Wfa){
    int idx = blockIdx.x*256 + threadIdx.x;   // 4*7*2*2*16*32 = 57344
    if (idx >= 57344) return;
    int j   = idx & 31;
    int l15 = (idx >> 5) & 15;
    int mt  = (idx >> 9) & 1;
    int q   = (idx >> 10) & 1;
    int k   = (idx >> 11) % 7;
    int w   = idx / 14336;
    int o = w*32 + mt*16 + l15;
    int cl = -1;
    if (q==1){ if (j < 30) cl = j + 2; }
    else     { if (j >= 30) cl = j - 30; }
    Wfa[idx] = (cl >= 0) ? Wfb[o*224 + cl*7 + k] : (ushort)0;
}

// ---------------- K6 v6: uT[n, y, x, o] = sum_k Wfa_k * t4T[n, y+2k-6, x, :] ----------------
// DMA pipeline: global_load_lds (16B) direct into 3 rotating LDS buffers, counted vmcnt.
template<int ST0, int NST>
__device__ __forceinline__ void t15_body_v6(const ushort* __restrict__ tbase, const ushort* __restrict__ Wfa,
                                            ushort* __restrict__ urow, int y, int w, int l15, int quad,
                                            ushort* lds){
    int qlo = (w+3)&3;
    int tid = threadIdx.x;
    float4v acc[NST][2] = {};
    int klo = (y >= 6) ? 0 : ((7 - y) >> 1);
    int khi = min(6, (117 - y) >> 1);
    int nk = khi - klo;              // >= 3 always

    const int swz = (tid>>4)&7;      // pi xor mask (depends only on tid bits 4..6)
    const int wbase = tid & ~63;     // wid*64: wave-uniform granule base within a j-chunk

    auto dma_row = [&](int k, int bufi){
        const ushort* rs = tbase + ((size_t)(y + 2*k - 6)*WW + ST0*16)*128;
        #pragma unroll
        for (int j=0;j<NST;j++){
            int g  = j*256 + tid;
            int gs = g ^ swz;                                  // pre-swizzled source granule
            const ushort* gp = rs + (size_t)gs*8;              // per-lane global addr
            ushort* lp = lds + (size_t)bufi*8192 + (size_t)(j*256 + wbase)*8;  // wave-uniform LDS base
            __builtin_amdgcn_global_load_lds((const __attribute__((address_space(1))) void*)gp,
                                             (__attribute__((address_space(3))) void*)lp, 16, 0, 0);
        }
    };
    auto issueA = [&](int k, short8v (&A)[4]){
        const ushort* af = Wfa + (w*7 + k)*2048 + l15*32 + quad*8;
        A[0] = *((const short8v*)(af));
        A[1] = *((const short8v*)(af + 512));
        A[2] = *((const short8v*)(af + 1024));
        A[3] = *((const short8v*)(af + 1536));
    };
    auto domm = [&](int bufi, const short8v (&A)[4]){
        const ushort* lb = lds + bufi*8192;
        #pragma unroll
        for (int st=0; st<NST; st++){
            int xl = st*16 + l15;
            int g0 = xl*16 + qlo*4 + quad;  g0 ^= (g0>>4)&7;
            int g1 = xl*16 + w*4   + quad;  g1 ^= (g1>>4)&7;
            short8v B0 = *((const short8v*)(lb + g0*8));
            short8v B1 = *((const short8v*)(lb + g1*8));
            acc[st][0] = __builtin_amdgcn_mfma_f32_16x16x32_bf16(A[0], B0, acc[st][0], 0,0,0);
            acc[st][1] = __builtin_amdgcn_mfma_f32_16x16x32_bf16(A[1], B0, acc[st][1], 0,0,0);
            acc[st][0] = __builtin_amdgcn_mfma_f32_16x16x32_bf16(A[2], B1, acc[st][0], 0,0,0);
            acc[st][1] = __builtin_amdgcn_mfma_f32_16x16x32_bf16(A[3], B1, acc[st][1], 0,0,0);
        }
    };
    auto iter = [&](int i, short8v (&Acur)[4], short8v (&Anx)[4]){
        // steady: rows i+1 (NST) + A (4) are the only ops newer than row i's DMA
        if (i+2 <= nk){
            if constexpr (NST==4) asm volatile("s_waitcnt vmcnt(8)" ::: "memory");
            else                  asm volatile("s_waitcnt vmcnt(7)" ::: "memory");
        } else {
            asm volatile("s_waitcnt vmcnt(0)" ::: "memory");
        }
        __builtin_amdgcn_s_barrier();
        __builtin_amdgcn_sched_barrier(0);
        if (i+1 <= nk) issueA(klo+i+1, Anx);
        if (i+2 <= nk) dma_row(klo+i+2, (i+2)%3);   // buffer last read at iter i-1; safe after this barrier
        domm(i%3, Acur);
    };

    short8v A0[4], A1[4];
    // prolog: rows klo, klo+1 in flight; A(klo) issued last
    dma_row(klo,   0);
    dma_row(klo+1, 1);
    issueA(klo, A0);

    for (int i=0; i<=nk; i+=2){
        iter(i, A0, A1);
        if (i+1 <= nk) iter(i+1, A1, A0);
    }

    // transposed store: uT[(y*WW + s)*128 + o] — wave w fills its 64B d-chunk of each 256B row
    #pragma unroll
    for (int st=0; st<NST; st++){
        int s = (ST0 + st)*16 + l15;
        ushort* p = urow + (size_t)s*128 + w*32 + quad*4;
        #pragma unroll
        for (int mt=0; mt<2; mt++){
            ushort4 v;
            v.x = f2bf(acc[st][mt][0]); v.y = f2bf(acc[st][mt][1]);
            v.z = f2bf(acc[st][mt][2]); v.w = f2bf(acc[st][mt][3]);
            *((ushort4*)(p + mt*16)) = v;
        }
    }
}
__global__ __launch_bounds__(256) void t15v6_k(const ushort* __restrict__ t4T, const ushort* __restrict__ Wfa,
                                               ushort* __restrict__ uT){
    __shared__ ushort lds[3*8192];     // 48KB: 3 x 16KB row-slice buffers
    int bx = blockIdx.x, n = blockIdx.y;   // bx in [0, 224)
    int xh = bx & 1, byi = bx >> 1;
    int y = (byi>>3) + (byi&7)*14;         // XCD-contiguous y chunks; x-halves paired
    int w = threadIdx.x >> 6, lane = threadIdx.x & 63;
    int l15 = lane & 15, quad = lane >> 4;
    const ushort* tbase = t4T + (size_t)n*PLANE;
    ushort* urow = uT + (size_t)n*PLANE + (size_t)y*WW*128;
    if (xh == 0) t15_body_v6<0,4>(tbase, Wfa, urow, y, w, l15, quad, lds);
    else         t15_body_v6<4,3>(tbase, Wfa, urow, y, w, l15, quad, lds);
}

// ---------------- K4 v6: t5part[ks][n][ci][cj] = sum_{s in 256-chunk} sigmoid(x[ci,s]) * x[cj,s] ----------------
// 512 threads / 8 waves: wave (shalf, wci) covers half the s-chunk x 32 ci. shalf=1 waves dump acc
// to LDS (stride RSTRIDE=130 -> exact 2-way, free); shalf=0 waves add + coalesced partial store.
// __shared__ hoisted to wrapper (single 66.5KB allocation -> 2 blocks/CU; R11's in-template
// declaration was duplicated per instantiation -> 132KB -> 1 block/CU).
template<typename ET>
__device__ __forceinline__ void t5mm_body(const ET* __restrict__ x, float* __restrict__ t5part, float* red){
    int ks = blockIdx.x, n = blockIdx.y;    // ks 0..48, 12544 = 49*256
    int tid = threadIdx.x;
    int wid = tid>>6, lane = tid&63;
    int l15 = lane&15, quad = lane>>4;
    int wci = wid & 3, shalf = wid >> 2;
    const ET* xn = x + (size_t)n*PLANE;
    float4v acc[2][8] = {};
    for (int t=0; t<4; t++){
        int sb = ks*256 + shalf*128 + t*32 + quad*8;
        short8v afr[2];
        #pragma unroll
        for (int mt=0; mt<2; mt++){
            int row = wci*32 + mt*16 + l15;
            float v[8]; ld8(xn + (size_t)row*HWS + sb, v);
            ushort tmp[8];
            #pragma unroll
            for (int j=0;j<8;j++) tmp[j] = f2bf(fsigmoid(v[j]));
            afr[mt] = *((const short8v*)tmp);
        }
        #pragma unroll
        for (int nt=0; nt<8; nt++){
            int row = nt*16 + l15;
            short8v bfr = ldbf(xn + (size_t)row*HWS + sb);
            acc[0][nt] = __builtin_amdgcn_mfma_f32_16x16x32_bf16(afr[0], bfr, acc[0][nt], 0,0,0);
            acc[1][nt] = __builtin_amdgcn_mfma_f32_16x16x32_bf16(afr[1], bfr, acc[1][nt], 0,0,0);
        }
    }
    if (shalf == 1){
        float* rp = red + wci*(32*RSTRIDE);
        #pragma unroll
        for (int mt=0; mt<2; mt++)
            #pragma unroll
            for (int nt=0; nt<8; nt++)
                #pragma unroll
                for (int r=0; r<4; r++){
                    int cil = mt*16 + quad*4 + r;
                    int cj  = nt*16 + l15;
                    rp[cil*RSTRIDE + cj] = acc[mt][nt][r];
                }
    }
    __syncthreads();
    if (shalf == 0){
        const float* rp = red + wci*(32*RSTRIDE);
        float* outp = t5part + (size_t)ks*(NB*16384) + (size_t)n*16384 + wci*32*128;
        #pragma unroll
        for (int mt=0; mt<2; mt++)
            #pragma unroll
            for (int nt=0; nt<8; nt++)
                #pragma unroll
                for (int r=0; r<4; r++){
                    int cil = mt*16 + quad*4 + r;
                    int cj  = nt*16 + l15;
                    outp[cil*128 + cj] = acc[mt][nt][r] + rp[cil*RSTRIDE + cj];
                }
    }
}
__global__ __launch_bounds__(512) void t5mm_k(const void* x, float* t5part, const int* fl){
    __shared__ float red[4*32*RSTRIDE];       // 66560 B, single allocation
    if (*fl) t5mm_body((const float*)x, t5part, red); else t5mm_body((const ushort*)x, t5part, red);
}

// ---------------- KC v2: coefb[n][d][c] = bf16(w9[c,d] * (sum_ks t5part[ks][n][c][d]) * sc) ----------------
template<typename ET>
__device__ __forceinline__ void coefb_body(const ET* __restrict__ w9, const float* __restrict__ t5part,
                                           ushort* __restrict__ coefb){
    const float sc = 7.89181775e-4f;   // 1/(sqrt(12544)*sqrt(128))
    int idx = blockIdx.x*256 + threadIdx.x;   // over 8*16384, input-contiguous
    int n = idx >> 14, rem = idx & 16383;
    int c = rem >> 7, d = rem & 127;
    const float* p = t5part + (size_t)n*16384 + rem;
    float s = 0.f;
    #pragma unroll 7
    for (int ks=0; ks<NSPLIT; ks++) s += p[(size_t)ks*(NB*16384)];
    coefb[n*16384 + d*128 + c] = f2bf(ldv(w9, c*128 + d) * s * sc);
}
__global__ __launch_bounds__(256) void coefb_k(const void* w9, const float* t5part, ushort* coefb, const int* fl){
    if (*fl) coefb_body((const float*)w9, t5part, coefb); else coefb_body((const ushort*)w9, t5part, coefb);
}

// ---------------- K5 (MFMA): out = uT[shifted] + coefb(128d x 128c) * silu(x)(128c x s) ----------------
template<typename OT>
__device__ __forceinline__ void final2_body(const ushort* __restrict__ Bpad, const ushort* __restrict__ coefb,
                                            const ushort* __restrict__ uT, OT* __restrict__ out){
    int sb = blockIdx.x, n = blockIdx.y;
    int wid = threadIdx.x>>6, lane = threadIdx.x&63;
    int l15 = lane&15, quad = lane>>4;
    int shalf = wid >> 1, ohalf = wid & 1;
    int s0 = sb*64 + shalf*32;
    int s1 = s0 + l15, s2 = s1 + 16;
    int y1 = s1/WW, x1 = s1 - y1*WW;
    int y2 = s2/WW, x2 = s2 - y2*WW;
    const ushort* bb = Bpad + (size_t)n*PLANEP;
    const ushort* b1p = bb + ((size_t)y1*XP + x1 + 2)*CC + quad*8;
    const ushort* b2p = bb + ((size_t)y2*XP + x2 + 2)*CC + quad*8;
    const ushort* abase = coefb + (size_t)n*16384 + (size_t)(ohalf*64 + l15)*128 + quad*8;
    float4v acc[4][2] = {};
    short8v bv0[4], bv1[4], aP[4], aQ[4];
    #pragma unroll
    for (int kc=0;kc<4;kc++){
        bv0[kc] = *((const short8v*)(b1p + kc*32));
        bv1[kc] = *((const short8v*)(b2p + kc*32));
    }
    auto lda = [&](int kc, short8v (&dst)[4]){
        #pragma unroll
        for (int mt=0;mt<4;mt++) dst[mt] = *((const short8v*)(abase + mt*16*128 + kc*32));
    };
    auto step = [&](const short8v (&a)[4], int kc){
        #pragma unroll
        for (int mt=0;mt<4;mt++){
            acc[mt][0] = __builtin_amdgcn_mfma_f32_16x16x32_bf16(a[mt], bv0[kc], acc[mt][0],0,0,0);
            acc[mt][1] = __builtin_amdgcn_mfma_f32_16x16x32_bf16(a[mt], bv1[kc], acc[mt][1],0,0,0);
        }
    };
    lda(0, aP);
    lda(1, aQ); step(aP, 0);
    lda(2, aP); step(aQ, 1);
    lda(3, aQ); step(aP, 2);
                step(aQ, 3);
    const ushort* uTn = uT + (size_t)n*PLANE;
    #pragma unroll
    for (int nt=0; nt<2; nt++){
        int s = s0 + nt*16 + l15;
        int y = s/WW, xx = s - y*WW;
        int ys = y+2; if (ys>=HH) ys-=HH;
        int xs = xx-2; if (xs<0) xs+=WW;
        const ushort* up = uTn + ((size_t)ys*WW + xs)*128 + ohalf*64 + quad*4;
        #pragma unroll
        for (int mt=0; mt<4; mt++){
            uint2 uv = *((const uint2*)(up + mt*16));
            float v0 = bflo(uv.x), vv1 = bfhi(uv.x), v2 = bflo(uv.y), v3 = bfhi(uv.y);
            int d = ohalf*64 + mt*16 + quad*4;
            stv(out, ((size_t)n*CC+d+0)*HWS + s, v0  + acc[mt][nt][0]);
            stv(out, ((size_t)n*CC+d+1)*HWS + s, vv1 + acc[mt][nt][1]);
            stv(out, ((size_t)n*CC+d+2)*HWS + s, v2  + acc[mt][nt][2]);
            stv(out, ((size_t)n*CC+d+3)*HWS + s, v3  + acc[mt][nt][3]);
        }
    }
}
__global__ __launch_bounds__(256) void final2_k(const ushort* Bpad, const ushort* coefb,
                                                const ushort* uT, void* out, const int* fl){
    if (*fl) final2_body(Bpad, coefb, uT, (float*)out);
    else     final2_body(Bpad, coefb, uT, (ushort*)out);
}

extern "C" void kernel_launch(void* const* d_in, const int* in_sizes, int n_in,
                              void* d_out, int out_size, void* d_ws, size_t ws_size,
                              hipStream_t stream) {
    const void* x   = d_in[0];
    const void* w3  = d_in[1];
    const void* w4  = d_in[2];
    const void* w9  = d_in[3];
    const void* w10 = d_in[4];
    const void* w15 = d_in[5];

    ushort* t3T  = (ushort*)d_ws;                  // TOT ushorts; 3 sequential lives:
    float*  t5part = (float*)t3T;                  //   (1) t3T (conv3mm->dwconvT), (2) t5part (t5mm->coefb),
    ushort* uT   = t3T;                            //   (3) uT (t15v6->final2). 49*8*16384*4B == 2*TOT B exactly.
    ushort* t4T  = t3T + TOT;                      // TOT ushorts
    ushort* Bpad = t4T + TOT;                      // NB*PLANEP ushorts (26.6MB; alive to the end)
    ushort* coefb= (ushort*)(Bpad + NB*PLANEP);    // 8*16384
    ushort* Wfb  = coefb + NB*CC*CC;               // 128*224
    ushort* Wpk  = Wfb + CC*224;                   // 128*384
    ushort* Wfa  = Wpk + CC*384;                   // 57344
    float*  wdp  = (float*)(Wfa + 57344);          // 896
    int* flag    = (int*)(wdp + 896);

    detect_k<<<1, 256, 0, stream>>>((const ushort*)x, flag);

    wpack_k  <<<192, 256, 0, stream>>>(w3, Wpk, flag);
    fusew_k  <<<112, 256, 0, stream>>>(w10, w15, Wfb, flag);
    wfapack_k<<<224, 256, 0, stream>>>(Wfb, Wfa);
    wdpack_k <<<4,   256, 0, stream>>>(w4, wdp, flag);
    bpad_k   <<<dim3(HH,NB), 256, 0, stream>>>(x, Bpad, flag);
    conv3mm_k<<<dim3(196,NB), 256, 0, stream>>>(Bpad, Wpk, t3T);
    dwconvT_k<<<dim3(HH,NB), 256, 0, stream>>>(t3T, wdp, t4T);
    t5mm_k   <<<dim3(NSPLIT,NB), 512, 0, stream>>>(x, t5part, flag);   // t5part aliases dead t3T
    coefb_k  <<<NB*CC*CC/256, 256, 0, stream>>>(w9, t5part, coefb, flag);
    t15v6_k  <<<dim3(224,NB), 256, 0, stream>>>(t4T, Wfa, uT);         // uT overwrites consumed t5part
    final2_k <<<dim3(196,NB), 256, 0, stream>>>(Bpad, coefb, uT, d_out, flag);
}

// Round 13
// 281.632 us; speedup vs baseline: 1.1291x; 1.0021x over previous
//
#include <hip/hip_runtime.h>
#include <hip/hip_bf16.h>

#define NB 8
#define CC 128
#define HH 112
#define WW 112
#define HWS (HH*WW)            // 12544
#define PLANE (CC*HWS)         // 1605632
#define TOT (NB*PLANE)         // 12845056
#define XP 116                 // padded x-extent: x+2k, x in [0,112), k in {0,1,2}
#define LROW 130               // LDS row stride in ushorts (65 words == 1 mod 32 -> conflict-free)
#define PLANEP ((size_t)HH*XP*CC)   // per-batch ushorts in Bpad = 1663488
#define NSPLIT 49              // t5 K-split; t5part = 49*8*16384 floats = 25690112 B = exactly 2*TOT bytes

typedef __attribute__((ext_vector_type(8))) short short8v;
typedef __attribute__((ext_vector_type(4))) float float4v;

__device__ __forceinline__ float bflo(unsigned u){ return __uint_as_float(u<<16); }
__device__ __forceinline__ float bfhi(unsigned u){ return __uint_as_float(u & 0xffff0000u); }
__device__ __forceinline__ float ldv(const float* p, size_t i){ return p[i]; }
__device__ __forceinline__ float ldv(const ushort* p, size_t i){ return __uint_as_float(((unsigned)p[i])<<16); }
__device__ __forceinline__ void ld8(const ushort* p, float* v){
    uint4 u0 = *((const uint4*)p);
    v[0]=bflo(u0.x); v[1]=bfhi(u0.x); v[2]=bflo(u0.y); v[3]=bfhi(u0.y);
    v[4]=bflo(u0.z); v[5]=bfhi(u0.z); v[6]=bflo(u0.w); v[7]=bfhi(u0.w);
}
__device__ __forceinline__ void ld8(const float* p, float* v){
    float4 a = *((const float4*)p); float4 b = *((const float4*)(p+4));
    v[0]=a.x; v[1]=a.y; v[2]=a.z; v[3]=a.w; v[4]=b.x; v[5]=b.y; v[6]=b.z; v[7]=b.w;
}
__device__ __forceinline__ void ld4(const float* p, float* v){
    float4 a = *((const float4*)p);
    v[0]=a.x; v[1]=a.y; v[2]=a.z; v[3]=a.w;
}
__device__ __forceinline__ void ld4(const ushort* p, float* v){
    uint2 u = *((const uint2*)p);
    v[0]=bflo(u.x); v[1]=bfhi(u.x); v[2]=bflo(u.y); v[3]=bfhi(u.y);
}
__device__ __forceinline__ ushort f2bf(float f){
    unsigned u = __float_as_uint(f);
    return (ushort)((u + 0x7fffu + ((u>>16)&1u)) >> 16);
}
__device__ __forceinline__ void stv(float* o, size_t i, float v){ o[i]=v; }
__device__ __forceinline__ void stv(ushort* o, size_t i, float v){ o[i]=f2bf(v); }
// fast sigmoid: 1/(1+e^-v) = rcp(1 + 2^(-v*log2e)); ~1ulp fp32 — invisible at bf16 output
__device__ __forceinline__ float fsigmoid(float v){
    float e = __builtin_amdgcn_exp2f(v * -1.44269504f);
    return __builtin_amdgcn_rcpf(1.f + e);
}
// raw bf16 fragment load (no convert round-trip) vs fp32 convert path
__device__ __forceinline__ short8v ldbf(const ushort* p){ return *((const short8v*)p); }
__device__ __forceinline__ short8v ldbf(const float* p){
    float v[8]; ld8(p, v);
    ushort tmp[8];
    #pragma unroll
    for (int j=0;j<8;j++) tmp[j]=f2bf(v[j]);
    return *((const short8v*)tmp);
}

// ---------------- K0: dtype probe. flag=1 -> inputs are fp32 ----------------
__global__ __launch_bounds__(256) void detect_k(const ushort* __restrict__ x, int* __restrict__ flag){
    __shared__ int cnt;
    if (threadIdx.x==0) cnt = 0;
    __syncthreads();
    int bad = 0;
    for (int i = threadIdx.x; i < 2048; i += 256){
        float v = ldv(x, i);
        if (!(v > -1e4f && v < 1e4f)) bad++;
    }
    atomicAdd(&cnt, bad);
    __syncthreads();
    if (threadIdx.x==0) *flag = (cnt > 64) ? 1 : 0;
}

// ---------------- KW1: Wpk[o][kappa=k*128+i] = bf16(w3[o,i,0,k]) ----------------
template<typename ET>
__device__ __forceinline__ void wpack_body(const ET* __restrict__ w3, ushort* __restrict__ Wpk){
    int idx = blockIdx.x*256 + threadIdx.x;
    if (idx < CC*384){
        int o = idx/384, kap = idx - o*384;
        int k = kap>>7, i = kap&127;
        Wpk[idx] = f2bf(ldv(w3, (o*128+i)*3 + k));
    }
}
__global__ __launch_bounds__(256) void wpack_k(const void* w3, ushort* Wpk, const int* fl){
    if (*fl) wpack_body((const float*)w3, Wpk); else wpack_body((const ushort*)w3, Wpk);
}

// ---------------- KB: Bpad[n][y][xp][i] = bf16(silu(x)[i, y, xp-2]), zeros at xp in {0,1,114,115} ----------
template<typename ET>
__device__ __forceinline__ void bpad_body(const ET* __restrict__ x, ushort* __restrict__ Bpad, ushort* px){
    int y = blockIdx.x, n = blockIdx.y;
    const ET* xb = x + (size_t)n*PLANE + y*WW;
    for (int idx=threadIdx.x; idx<CC*28; idx+=256){      // x4-vectorized global reads
        int i = idx/28, xq = (idx - i*28)*4;
        float v[4]; ld4(xb + (size_t)i*HWS + xq, v);
        #pragma unroll
        for (int d=0;d<4;d++){
            float vv = v[d];
            px[(xq+d+2)*LROW + i] = f2bf(vv * fsigmoid(vv));
        }
    }
    for (int idx=threadIdx.x; idx<4*CC; idx+=256){
        int j = idx >> 7, i = idx & 127;
        int xp = (j<2) ? j : j+112;               // 0,1,114,115
        px[xp*LROW + i] = 0;
    }
    __syncthreads();
    ushort* ob = Bpad + ((size_t)n*HH + y)*XP*CC;
    for (int idx=threadIdx.x; idx<XP*16; idx+=256){
        int xp = idx >> 4, c8 = idx & 15;
        const ushort* pr = px + xp*LROW + c8*8;   // even ushort index -> 4B aligned
        uint4 v;
        v.x = *((const uint*)(pr+0));
        v.y = *((const uint*)(pr+2));
        v.z = *((const uint*)(pr+4));
        v.w = *((const uint*)(pr+6));
        *((uint4*)(ob + (size_t)xp*CC + c8*8)) = v;   // fully coalesced 1KB/wave
    }
}
__global__ __launch_bounds__(256) void bpad_k(const void* x, ushort* Bpad, const int* fl){
    __shared__ ushort px[XP*LROW];                 // 30160 B, single allocation (hoisted: R11 lesson)
    if (*fl) bpad_body((const float*)x, Bpad, px); else bpad_body((const ushort*)x, Bpad, px);
}

// ---------------- K2: t3T[n][s][o] = A(128x384) * B(384 x s) — A in LDS, deep B prefetch ----------------
__global__ __launch_bounds__(256) void conv3mm_k(const ushort* __restrict__ Bpad, const ushort* __restrict__ Wpk,
                                                 ushort* __restrict__ t3T){
    int bx = blockIdx.x;        // 0..195
    int n  = blockIdx.y;
    int sbi = bx >> 1, oh = bx & 1;
    int wid = threadIdx.x >> 6, lane = threadIdx.x & 63;
    int l15 = lane & 15, quad = lane >> 4;
    __shared__ ushort Alds[24576];           // 48KB
    {   // cooperative stage: granule g -> (kcmt, l15, quad); 12 x 16B per thread, all in flight
        const int tid = threadIdx.x;
        uint4 tmp[12];
        #pragma unroll
        for (int it=0; it<12; it++){
            int g = it*256 + tid;
            int kcmt = g >> 6, sl = (g>>2)&15, sq = g&3;
            int kc = kcmt >> 2, mt = kcmt & 3;
            tmp[it] = *((const uint4*)(Wpk + (size_t)(oh*64 + mt*16 + sl)*384 + kc*32 + sq*8));
        }
        #pragma unroll
        for (int it=0; it<12; it++){
            int g = it*256 + tid;
            *((uint4*)(Alds + g*8)) = tmp[it];
        }
    }
    __syncthreads();

    int s0 = sbi*128 + wid*32;
    int s1 = s0 + l15, s2 = s1 + 16;
    int y1 = s1/WW, x1 = s1 - y1*WW;
    int y2 = s2/WW, x2 = s2 - y2*WW;
    const ushort* bb = Bpad + (size_t)n*PLANEP;
    const ushort* b1p = bb + ((size_t)y1*XP + x1)*CC + quad*8;
    const ushort* b2p = bb + ((size_t)y2*XP + x2)*CC + quad*8;
    const ushort* al = Alds + l15*32 + quad*8;

    float4v acc[4][2] = {};
    short8v BA[2][4], BB[2][4], a0[4], a1[4];

    auto ldb = [&](int g, short8v (&B)[2][4]){
        #pragma unroll
        for (int m=0;m<4;m++){
            B[0][m] = *((const short8v*)(b1p + g*256 + m*32));
            B[1][m] = *((const short8v*)(b2p + g*256 + m*32));
        }
    };
    auto lda = [&](int kc, short8v (&dst)[4]){
        #pragma unroll
        for (int mt=0;mt<4;mt++) dst[mt] = *((const short8v*)(al + (kc*4+mt)*512));
    };
    auto step = [&](const short8v (&a)[4], const short8v (&B)[2][4], int m){
        #pragma unroll
        for (int mt=0;mt<4;mt++){
            acc[mt][0] = __builtin_amdgcn_mfma_f32_16x16x32_bf16(a[mt], B[0][m], acc[mt][0],0,0,0);
            acc[mt][1] = __builtin_amdgcn_mfma_f32_16x16x32_bf16(a[mt], B[1][m], acc[mt][1],0,0,0);
        }
    };

    ldb(0, BA); lda(0, a0);
    ldb(1, BB);
    lda(1, a1);  step(a0, BA, 0);   // kc0
    lda(2, a0);  step(a1, BA, 1);   // kc1
    lda(3, a1);  step(a0, BA, 2);   // kc2
    lda(4, a0);  step(a1, BA, 3);   // kc3
    ldb(2, BA);                     // region 2 (BA free)
    lda(5, a1);  step(a0, BB, 0);   // kc4
    lda(6, a0);  step(a1, BB, 1);   // kc5
    lda(7, a1);  step(a0, BB, 2);   // kc6
    lda(8, a0);  step(a1, BB, 3);   // kc7
    lda(9, a1);  step(a0, BA, 0);   // kc8
    lda(10, a0); step(a1, BA, 1);   // kc9
    lda(11, a1); step(a0, BA, 2);   // kc10
                 step(a1, BA, 3);   // kc11

    ushort* tb = t3T + (size_t)n*PLANE;
    #pragma unroll
    for (int nt=0; nt<2; nt++){
        int s = s0 + nt*16 + l15;
        ushort* rowp = tb + (size_t)s*128 + oh*64 + quad*4;
        #pragma unroll
        for (int mt=0; mt<4; mt++){
            ushort4 v;
            v.x = f2bf(acc[mt][nt][0]); v.y = f2bf(acc[mt][nt][1]);
            v.z = f2bf(acc[mt][nt][2]); v.w = f2bf(acc[mt][nt][3]);
            *((ushort4*)(rowp + mt*16)) = v;
        }
    }
}

// ---------------- KWD: wdp[k*128+c] = w4[c,k] (fp32) ----------------
template<typename ET>
__device__ __forceinline__ void wdpack_body(const ET* __restrict__ w4, float* __restrict__ wdp){
    int idx = blockIdx.x*256 + threadIdx.x;
    if (idx < 896){ int k = idx >> 7, c = idx & 127; wdp[idx] = ldv(w4, c*7 + k); }
}
__global__ __launch_bounds__(256) void wdpack_k(const void* w4, float* wdp, const int* fl){
    if (*fl) wdpack_body((const float*)w4, wdp); else wdpack_body((const ushort*)w4, wdp);
}

// ---------------- K3: depthwise conv(7,1) dil=(3,1) pad=(9,0) on transposed layout, LDS-free ----------------
__global__ __launch_bounds__(256) void dwconvT_k(const ushort* __restrict__ t3T, const float* __restrict__ wdp,
                                                 ushort* __restrict__ t4T){
    int by = blockIdx.x, n = blockIdx.y;
    int y = (by>>3) + (by&7)*14;   // XCD-contiguous y chunks
    const ushort* tb = t3T + (size_t)n*PLANE;
    ushort* ob = t4T + (size_t)n*PLANE + (size_t)y*WW*128;
    for (int it = threadIdx.x; it < WW*16; it += 256){
        int c8 = it & 15, x = it >> 4;
        int coff = c8*8;
        float acc8[8] = {0.f,0.f,0.f,0.f,0.f,0.f,0.f,0.f};
        #pragma unroll
        for (int k=0;k<7;k++){
            int row = y - 9 + 3*k;
            if (row < 0 || row >= HH) continue;
            float v[8]; ld8(tb + ((size_t)row*WW + x)*128 + coff, v);
            const float* wp = wdp + k*128 + coff;
            #pragma unroll
            for (int j=0;j<8;j++) acc8[j] = fmaf(wp[j], v[j], acc8[j]);
        }
        ushort tmp[8];
        #pragma unroll
        for (int j=0;j<8;j++) tmp[j] = f2bf(acc8[j]);
        *((short8v*)(ob + (size_t)x*128 + coff)) = *((const short8v*)tmp);
    }
}

// ---------------- KW2: Wfb[o][cl*7+k] = bf16(w15[o, cl*7+k] * w10[32g+cl, k]) ----------------
template<typename ET>
__device__ __forceinline__ void fusew_body(const ET* __restrict__ w10, const ET* __restrict__ w15,
                                           ushort* __restrict__ Wfb){
    int idx = blockIdx.x*256+threadIdx.x;
    if (idx < CC*224){
        int o = idx / 224, r = idx - o*224;
        int g = o >> 5;
        int cl = r/7, k = r - cl*7;
        int c = g*32 + cl;
        Wfb[idx] = f2bf(ldv(w15, o*224 + r) * ldv(w10, c*7+k));
    }
}
__global__ __launch_bounds__(256) void fusew_k(const void* w10, const void* w15, ushort* Wfb, const int* fl){
    if (*fl) fusew_body((const float*)w10, (const float*)w15, Wfb);
    else     fusew_body((const ushort*)w10, (const ushort*)w15, Wfb);
}

// ---------------- KWA: Wfa fragment pack. A[w][k][q][mt][l15][j] over c'-aligned 32-blocks ----------------
__global__ __launch_bounds__(256) void wfapack_k(const ushort* __restrict__ Wfb, ushort* __restrict__ Wfa){
    int idx = blockIdx.x*256 + threadIdx.x;   // 4*7*2*2*16*32 = 57344
    if (idx >= 57344) return;
    int j   = idx & 31;
    int l15 = (idx >> 5) & 15;
    int mt  = (idx >> 9) & 1;
    int q   = (idx >> 10) & 1;
    int k   = (idx >> 11) % 7;
    int w   = idx / 14336;
    int o = w*32 + mt*16 + l15;
    int cl = -1;
    if (q==1){ if (j < 30) cl = j + 2; }
    else     { if (j >= 30) cl = j - 30; }
    Wfa[idx] = (cl >= 0) ? Wfb[o*224 + cl*7 + k] : (ushort)0;
}

// ---------------- K6 v6: uT[n, y, x, o] = sum_k Wfa_k * t4T[n, y+2k-6, x, :] ----------------
// DMA pipeline: global_load_lds (16B) direct into 3 rotating LDS buffers, counted vmcnt.
// vmcnt steady-state = NST (one row in flight): guarantees row i landed at iter i (R12 audit:
// the old 2*NST count only guaranteed row i-1 and worked by timing luck).
template<int ST0, int NST>
__device__ __forceinline__ void t15_body_v6(const ushort* __restrict__ tbase, const ushort* __restrict__ Wfa,
                                            ushort* __restrict__ urow, int y, int w, int l15, int quad,
                                            ushort* lds){
    int qlo = (w+3)&3;
    int tid = threadIdx.x;
    float4v acc[NST][2] = {};
    int klo = (y >= 6) ? 0 : ((7 - y) >> 1);
    int khi = min(6, (117 - y) >> 1);
    int nk = khi - klo;              // >= 3 always

    const int swz = (tid>>4)&7;      // pi xor mask (depends only on tid bits 4..6)
    const int wbase = tid & ~63;     // wid*64: wave-uniform granule base within a j-chunk

    auto dma_row = [&](int k, int bufi){
        const ushort* rs = tbase + ((size_t)(y + 2*k - 6)*WW + ST0*16)*128;
        #pragma unroll
        for (int j=0;j<NST;j++){
            int g  = j*256 + tid;
            int gs = g ^ swz;                                  // pre-swizzled source granule
            const ushort* gp = rs + (size_t)gs*8;              // per-lane global addr
            ushort* lp = lds + (size_t)bufi*8192 + (size_t)(j*256 + wbase)*8;  // wave-uniform LDS base
            __builtin_amdgcn_global_load_lds((const __attribute__((address_space(1))) void*)gp,
                                             (__attribute__((address_space(3))) void*)lp, 16, 0, 0);
        }
    };
    auto issueA = [&](int k, short8v (&A)[4]){
        const ushort* af = Wfa + (w*7 + k)*2048 + l15*32 + quad*8;
        A[0] = *((const short8v*)(af));
        A[1] = *((const short8v*)(af + 512));
        A[2] = *((const short8v*)(af + 1024));
        A[3] = *((const short8v*)(af + 1536));
    };
    auto domm = [&](int bufi, const short8v (&A)[4]){
        const ushort* lb = lds + bufi*8192;
        #pragma unroll
        for (int st=0; st<NST; st++){
            int xl = st*16 + l15;
            int g0 = xl*16 + qlo*4 + quad;  g0 ^= (g0>>4)&7;
            int g1 = xl*16 + w*4   + quad;  g1 ^= (g1>>4)&7;
            short8v B0 = *((const short8v*)(lb + g0*8));
            short8v B1 = *((const short8v*)(lb + g1*8));
            acc[st][0] = __builtin_amdgcn_mfma_f32_16x16x32_bf16(A[0], B0, acc[st][0], 0,0,0);
            acc[st][1] = __builtin_amdgcn_mfma_f32_16x16x32_bf16(A[1], B0, acc[st][1], 0,0,0);
            acc[st][0] = __builtin_amdgcn_mfma_f32_16x16x32_bf16(A[2], B1, acc[st][0], 0,0,0);
            acc[st][1] = __builtin_amdgcn_mfma_f32_16x16x32_bf16(A[3], B1, acc[st][1], 0,0,0);
        }
    };
    auto iter = [&](int i, short8v (&Acur)[4], short8v (&Anx)[4]){
        // steady: only row i+1 (NST instr) may remain outstanding -> row i guaranteed landed
        if (i+1 <= nk){
            if constexpr (NST==4) asm volatile("s_waitcnt vmcnt(4)" ::: "memory");
            else                  asm volatile("s_waitcnt vmcnt(3)" ::: "memory");
        } else {
            asm volatile("s_waitcnt vmcnt(0)" ::: "memory");
        }
        __builtin_amdgcn_s_barrier();
        __builtin_amdgcn_sched_barrier(0);
        if (i+1 <= nk) issueA(klo+i+1, Anx);
        if (i+2 <= nk) dma_row(klo+i+2, (i+2)%3);   // buffer last read at iter i-1; safe after this barrier
        domm(i%3, Acur);
    };

    short8v A0[4], A1[4];
    // prolog: rows klo, klo+1 in flight; A(klo) issued last
    dma_row(klo,   0);
    dma_row(klo+1, 1);
    issueA(klo, A0);

    for (int i=0; i<=nk; i+=2){
        iter(i, A0, A1);
        if (i+1 <= nk) iter(i+1, A1, A0);
    }

    // transposed store: uT[(y*WW + s)*128 + o] — wave w fills its 64B d-chunk of each 256B row
    #pragma unroll
    for (int st=0; st<NST; st++){
        int s = (ST0 + st)*16 + l15;
        ushort* p = urow + (size_t)s*128 + w*32 + quad*4;
        #pragma unroll
        for (int mt=0; mt<2; mt++){
            ushort4 v;
            v.x = f2bf(acc[st][mt][0]); v.y = f2bf(acc[st][mt][1]);
            v.z = f2bf(acc[st][mt][2]); v.w = f2bf(acc[st][mt][3]);
            *((ushort4*)(p + mt*16)) = v;
        }
    }
}
__global__ __launch_bounds__(256) void t15v6_k(const ushort* __restrict__ t4T, const ushort* __restrict__ Wfa,
                                               ushort* __restrict__ uT){
    __shared__ ushort lds[3*8192];     // 48KB: 3 x 16KB row-slice buffers
    int bx = blockIdx.x, n = blockIdx.y;   // bx in [0, 224)
    int xh = bx & 1, byi = bx >> 1;
    int y = (byi>>3) + (byi&7)*14;         // XCD-contiguous y chunks; x-halves paired
    int w = threadIdx.x >> 6, lane = threadIdx.x & 63;
    int l15 = lane & 15, quad = lane >> 4;
    const ushort* tbase = t4T + (size_t)n*PLANE;
    ushort* urow = uT + (size_t)n*PLANE + (size_t)y*WW*128;
    if (xh == 0) t15_body_v6<0,4>(tbase, Wfa, urow, y, w, l15, quad, lds);
    else         t15_body_v6<4,3>(tbase, Wfa, urow, y, w, l15, quad, lds);
}

// ---------------- K4 v7: t5part[ks][n][ci][cj] via DMA-staged LDS pipeline (bf16 path) ----------------
// Per block (ks,n): 8 slices of 32 s x 128 ch (8KB) staged via global_load_lds into 3 buffers,
// counted vmcnt(2) + raw s_barrier (t15v6-proven schedule). A (sigmoid) and B (raw) fragments
// both read from LDS: one staged copy shared by 4 waves instead of 4 redundant global streams.
// Swizzle (both-sides involution): slot g holds global granule (ch=g>>2, part=(g&3)^((g>>3)&3));
// read slot for (row,quad) = row*4 + (quad^((row>>1)&3)) -> 2 lanes/bank on ds_read_b128 (free).
__device__ __forceinline__ void t5mm_dma_body(const ushort* __restrict__ x, float* __restrict__ t5part,
                                              ushort* lds){
    int ks = blockIdx.x, n = blockIdx.y;    // ks 0..48, 12544 = 49*256
    int tid = threadIdx.x;
    int wid = tid>>6, lane = tid&63;
    int l15 = lane&15, quad = lane>>4;
    const ushort* xn = x + (size_t)n*PLANE;
    const int sb0 = ks*256;
    const int wbase = tid & ~63;
    float4v acc[2][8] = {};

    auto dma = [&](int t, int bufi){
        #pragma unroll
        for (int j=0;j<2;j++){
            int g  = j*256 + tid;                 // slot index; 512 slots of 16B per slice
            int ch = g>>2;
            int pp = (g&3) ^ ((g>>3)&3);          // pre-swizzled source part
            const ushort* gp = xn + (size_t)ch*HWS + sb0 + t*32 + pp*8;
            ushort* lp = lds + (size_t)bufi*4096 + (size_t)(j*256 + wbase)*8;  // wave-uniform base
            __builtin_amdgcn_global_load_lds((const __attribute__((address_space(1))) void*)gp,
                                             (__attribute__((address_space(3))) void*)lp, 16, 0, 0);
        }
    };
    auto domm = [&](int bufi){
        const ushort* lb = lds + bufi*4096;
        short8v afr[2];
        #pragma unroll
        for (int mt=0; mt<2; mt++){
            int row = wid*32 + mt*16 + l15;
            int g = row*4 + (quad ^ ((row>>1)&3));
            uint4 u = *((const uint4*)(lb + g*8));
            float v[8];
            v[0]=bflo(u.x); v[1]=bfhi(u.x); v[2]=bflo(u.y); v[3]=bfhi(u.y);
            v[4]=bflo(u.z); v[5]=bfhi(u.z); v[6]=bflo(u.w); v[7]=bfhi(u.w);
            ushort tmp[8];
            #pragma unroll
            for (int j=0;j<8;j++) tmp[j] = f2bf(fsigmoid(v[j]));
            afr[mt] = *((const short8v*)tmp);
        }
        #pragma unroll
        for (int nt=0; nt<8; nt++){
            int row = nt*16 + l15;
            int g = row*4 + (quad ^ ((row>>1)&3));
            short8v bfr = *((const short8v*)(lb + g*8));
            acc[0][nt] = __builtin_amdgcn_mfma_f32_16x16x32_bf16(afr[0], bfr, acc[0][nt], 0,0,0);
            acc[1][nt] = __builtin_amdgcn_mfma_f32_16x16x32_bf16(afr[1], bfr, acc[1][nt], 0,0,0);
        }
    };

    dma(0, 0);
    dma(1, 1);
    #pragma unroll
    for (int i=0; i<8; i++){
        if (i < 7) asm volatile("s_waitcnt vmcnt(2)" ::: "memory");   // slice i landed; i+1 in flight
        else       asm volatile("s_waitcnt vmcnt(0)" ::: "memory");
        __builtin_amdgcn_s_barrier();
        __builtin_amdgcn_sched_barrier(0);
        if (i+2 <= 7) dma(i+2, (i+2)%3);          // buffer last read at iter i-1; safe post-barrier
        domm(i%3);
    }

    float* outp = t5part + (size_t)ks*(NB*16384) + (size_t)n*16384;
    #pragma unroll
    for (int mt=0; mt<2; mt++){
        #pragma unroll
        for (int nt=0; nt<8; nt++){
            #pragma unroll
            for (int r=0; r<4; r++){
                int ci = wid*32 + mt*16 + quad*4 + r;
                int cj = nt*16 + l15;
                outp[ci*128 + cj] = acc[mt][nt][r];
            }
        }
    }
}
// fp32 fallback (not exercised by the bf16 bench): global-load variant (R10 structure)
__device__ __forceinline__ void t5mm_f32_body(const float* __restrict__ x, float* __restrict__ t5part){
    int ks = blockIdx.x, n = blockIdx.y;
    int wid = threadIdx.x>>6, lane = threadIdx.x&63;
    int l15 = lane&15, quad = lane>>4;
    const float* xn = x + (size_t)n*PLANE;
    float4v acc[2][8] = {};
    for (int t=0; t<8; t++){
        int sb = ks*256 + t*32 + quad*8;
        short8v afr[2];
        #pragma unroll
        for (int mt=0; mt<2; mt++){
            int row = wid*32 + mt*16 + l15;
            float v[8]; ld8(xn + (size_t)row*HWS + sb, v);
            ushort tmp[8];
            #pragma unroll
            for (int j=0;j<8;j++) tmp[j] = f2bf(fsigmoid(v[j]));
            afr[mt] = *((const short8v*)tmp);
        }
        #pragma unroll
        for (int nt=0; nt<8; nt++){
            int row = nt*16 + l15;
            short8v bfr = ldbf(xn + (size_t)row*HWS + sb);
            acc[0][nt] = __builtin_amdgcn_mfma_f32_16x16x32_bf16(afr[0], bfr, acc[0][nt], 0,0,0);
            acc[1][nt] = __builtin_amdgcn_mfma_f32_16x16x32_bf16(afr[1], bfr, acc[1][nt], 0,0,0);
        }
    }
    float* outp = t5part + (size_t)ks*(NB*16384) + (size_t)n*16384;
    #pragma unroll
    for (int mt=0; mt<2; mt++){
        #pragma unroll
        for (int nt=0; nt<8; nt++){
            #pragma unroll
            for (int r=0; r<4; r++){
                int ci = wid*32 + mt*16 + quad*4 + r;
                int cj = nt*16 + l15;
                outp[ci*128 + cj] = acc[mt][nt][r];
            }
        }
    }
}
__global__ __launch_bounds__(256) void t5mm_k(const void* x, float* t5part, const int* fl){
    __shared__ ushort lds[3*4096];            // 24KB, single allocation (hoisted)
    if (*fl) t5mm_f32_body((const float*)x, t5part);
    else     t5mm_dma_body((const ushort*)x, t5part, lds);
}

// ---------------- KC v2: coefb[n][d][c] = bf16(w9[c,d] * (sum_ks t5part[ks][n][c][d]) * sc) ----------------
template<typename ET>
__device__ __forceinline__ void coefb_body(const ET* __restrict__ w9, const float* __restrict__ t5part,
                                           ushort* __restrict__ coefb){
    const float sc = 7.89181775e-4f;   // 1/(sqrt(12544)*sqrt(128))
    int idx = blockIdx.x*256 + threadIdx.x;   // over 8*16384, input-contiguous
    int n = idx >> 14, rem = idx & 16383;
    int c = rem >> 7, d = rem & 127;
    const float* p = t5part + (size_t)n*16384 + rem;
    float s = 0.f;
    #pragma unroll 7
    for (int ks=0; ks<NSPLIT; ks++) s += p[(size_t)ks*(NB*16384)];
    coefb[n*16384 + d*128 + c] = f2bf(ldv(w9, c*128 + d) * s * sc);
}
__global__ __launch_bounds__(256) void coefb_k(const void* w9, const float* t5part, ushort* coefb, const int* fl){
    if (*fl) coefb_body((const float*)w9, t5part, coefb); else coefb_body((const ushort*)w9, t5part, coefb);
}

// ---------------- K5 (MFMA): out = uT[shifted] + coefb(128d x 128c) * silu(x)(128c x s) ----------------
template<typename OT>
__device__ __forceinline__ void final2_body(const ushort* __restrict__ Bpad, const ushort* __restrict__ coefb,
                                            const ushort* __restrict__ uT, OT* __restrict__ out){
    int sb = blockIdx.x, n = blockIdx.y;
    int wid = threadIdx.x>>6, lane = threadIdx.x&63;
    int l15 = lane&15, quad = lane>>4;
    int shalf = wid >> 1, ohalf = wid & 1;
    int s0 = sb*64 + shalf*32;
    int s1 = s0 + l15, s2 = s1 + 16;
    int y1 = s1/WW, x1 = s1 - y1*WW;
    int y2 = s2/WW, x2 = s2 - y2*WW;
    const ushort* bb = Bpad + (size_t)n*PLANEP;
    const ushort* b1p = bb + ((size_t)y1*XP + x1 + 2)*CC + quad*8;
    const ushort* b2p = bb + ((size_t)y2*XP + x2 + 2)*CC + quad*8;
    const ushort* abase = coefb + (size_t)n*16384 + (size_t)(ohalf*64 + l15)*128 + quad*8;
    float4v acc[4][2] = {};
    short8v bv0[4], bv1[4], aP[4], aQ[4];
    #pragma unroll
    for (int kc=0;kc<4;kc++){
        bv0[kc] = *((const short8v*)(b1p + kc*32));
        bv1[kc] = *((const short8v*)(b2p + kc*32));
    }
    auto lda = [&](int kc, short8v (&dst)[4]){
        #pragma unroll
        for (int mt=0;mt<4;mt++) dst[mt] = *((const short8v*)(abase + mt*16*128 + kc*32));
    };
    auto step = [&](const short8v (&a)[4], int kc){
        #pragma unroll
        for (int mt=0;mt<4;mt++){
            acc[mt][0] = __builtin_amdgcn_mfma_f32_16x16x32_bf16(a[mt], bv0[kc], acc[mt][0],0,0,0);
            acc[mt][1] = __builtin_amdgcn_mfma_f32_16x16x32_bf16(a[mt], bv1[kc], acc[mt][1],0,0,0);
        }
    };
    lda(0, aP);
    lda(1, aQ); step(aP, 0);
    lda(2, aP); step(aQ, 1);
    lda(3, aQ); step(aP, 2);
                step(aQ, 3);
    const ushort* uTn = uT + (size_t)n*PLANE;
    #pragma unroll
    for (int nt=0; nt<2; nt++){
        int s = s0 + nt*16 + l15;
        int y = s/WW, xx = s - y*WW;
        int ys = y+2; if (ys>=HH) ys-=HH;
        int xs = xx-2; if (xs<0) xs+=WW;
        const ushort* up = uTn + ((size_t)ys*WW + xs)*128 + ohalf*64 + quad*4;
        #pragma unroll
        for (int mt=0; mt<4; mt++){
            uint2 uv = *((const uint2*)(up + mt*16));
            float v0 = bflo(uv.x), vv1 = bfhi(uv.x), v2 = bflo(uv.y), v3 = bfhi(uv.y);
            int d = ohalf*64 + mt*16 + quad*4;
            stv(out, ((size_t)n*CC+d+0)*HWS + s, v0  + acc[mt][nt][0]);
            stv(out, ((size_t)n*CC+d+1)*HWS + s, vv1 + acc[mt][nt][1]);
            stv(out, ((size_t)n*CC+d+2)*HWS + s, v2  + acc[mt][nt][2]);
            stv(out, ((size_t)n*CC+d+3)*HWS + s, v3  + acc[mt][nt][3]);
        }
    }
}
__global__ __launch_bounds__(256) void final2_k(const ushort* Bpad, const ushort* coefb,
                                                const ushort* uT, void* out, const int* fl){
    if (*fl) final2_body(Bpad, coefb, uT, (float*)out);
    else     final2_body(Bpad, coefb, uT, (ushort*)out);
}

extern "C" void kernel_launch(void* const* d_in, const int* in_sizes, int n_in,
                              void* d_out, int out_size, void* d_ws, size_t ws_size,
                              hipStream_t stream) {
    const void* x   = d_in[0];
    const void* w3  = d_in[1];
    const void* w4  = d_in[2];
    const void* w9  = d_in[3];
    const void* w10 = d_in[4];
    const void* w15 = d_in[5];

    ushort* t3T  = (ushort*)d_ws;                  // TOT ushorts; 3 sequential lives:
    float*  t5part = (float*)t3T;                  //   (1) t3T (conv3mm->dwconvT), (2) t5part (t5mm->coefb),
    ushort* uT   = t3T;                            //   (3) uT (t15v6->final2). 49*8*16384*4B == 2*TOT B exactly.
    ushort* t4T  = t3T + TOT;                      // TOT ushorts
    ushort* Bpad = t4T + TOT;                      // NB*PLANEP ushorts (26.6MB; alive to the end)
    ushort* coefb= (ushort*)(Bpad + NB*PLANEP);    // 8*16384
    ushort* Wfb  = coefb + NB*CC*CC;               // 128*224
    ushort* Wpk  = Wfb + CC*224;                   // 128*384
    ushort* Wfa  = Wpk + CC*384;                   // 57344
    float*  wdp  = (float*)(Wfa + 57344);          // 896
    int* flag    = (int*)(wdp + 896);

    detect_k<<<1, 256, 0, stream>>>((const ushort*)x, flag);

    wpack_k  <<<192, 256, 0, stream>>>(w3, Wpk, flag);
    fusew_k  <<<112, 256, 0, stream>>>(w10, w15, Wfb, flag);
    wfapack_k<<<224, 256, 0, stream>>>(Wfb, Wfa);
    wdpack_k <<<4,   256, 0, stream>>>(w4, wdp, flag);
    bpad_k   <<<dim3(HH,NB), 256, 0, stream>>>(x, Bpad, flag);
    conv3mm_k<<<dim3(196,NB), 256, 0, stream>>>(Bpad, Wpk, t3T);
    dwconvT_k<<<dim3(HH,NB), 256, 0, stream>>>(t3T, wdp, t4T);
    t5mm_k   <<<dim3(NSPLIT,NB), 256, 0, stream>>>(x, t5part, flag);   // t5part aliases dead t3T
    coefb_k  <<<NB*CC*CC/256, 256, 0, stream>>>(w9, t5part, coefb, flag);
    t15v6_k  <<<dim3(224,NB), 256, 0, stream>>>(t4T, Wfa, uT);         // uT overwrites consumed t5part
    final2_k <<<dim3(196,NB), 256, 0, stream>>>(Bpad, coefb, uT, d_out, flag);
}